// Round 4
// baseline (2309.381 us; speedup 1.0000x reference)
//
#include <hip/hip_runtime.h>
#include <hip/hip_bf16.h>
#include <cstdint>

constexpr int IN_DIM = 768;

typedef __attribute__((ext_vector_type(8))) short bf16x8;
typedef __attribute__((ext_vector_type(4))) float f32x4;

static __device__ __forceinline__ float leaky_(float x){ return x >= 0.0f ? x : 0.01f * x; }

static __device__ __forceinline__ float wsum_(float v){
#pragma unroll
  for (int m = 1; m < 64; m <<= 1) v += __shfl_xor(v, m, 64);
  return v;
}

static __device__ __forceinline__ float wln_(float v, float g, float be){
  float mu  = wsum_(v) * 0.015625f;
  float c   = v - mu;
  float var = wsum_(c * c) * 0.015625f;
  return c * rsqrtf(var + 1e-5f) * g + be;
}

static __device__ __forceinline__ unsigned short f2bf(float x){
  return __bfloat16_as_ushort(__float2bfloat16(x));
}
static __device__ __forceinline__ float bf2f(unsigned short u){
  return __bfloat162float(__ushort_as_bfloat16(u));
}
static __device__ __forceinline__ void split4(const float4 a, ushort4& hi, ushort4& lo){
  hi.x = f2bf(a.x); lo.x = f2bf(a.x - bf2f(hi.x));
  hi.y = f2bf(a.y); lo.y = f2bf(a.y - bf2f(hi.y));
  hi.z = f2bf(a.z); lo.z = f2bf(a.z - bf2f(hi.z));
  hi.w = f2bf(a.w); lo.w = f2bf(a.w - bf2f(hi.w));
}

// ---------------- weight prep: split-bf16 fragment tables ----------------
// Frag (kt,n): lane l holds W[kt*32 + (l>>4)*8 + j][n*16 + (l&15)], j=0..7.
// Table: [Wf0:16][Wb0:16][Wf1:16][Wb1:16][euW0:24] frags, 512 ushort each.
__global__ __launch_bounds__(256) void k_wprep(
    const float* __restrict__ Wf, const float* __restrict__ Wb,
    const float* __restrict__ euW,
    unsigned short* __restrict__ Fhi, unsigned short* __restrict__ Flo)
{
  const int gt = blockIdx.x * 256 + threadIdx.x;
  if (gt >= 88 * 64) return;
  const int fid = gt >> 6, lane = gt & 63;
  const float* src; int lf;
  if (fid < 16)      { src = Wf;            lf = fid;      }
  else if (fid < 32) { src = Wb;            lf = fid - 16; }
  else if (fid < 48) { src = Wf + 128 * 64; lf = fid - 32; }
  else if (fid < 64) { src = Wb + 128 * 64; lf = fid - 48; }
  else               { src = euW;           lf = fid - 64; }
  const int kt = lf >> 2, n = lf & 3;
  const int col = n * 16 + (lane & 15);
  const int r0  = kt * 32 + (lane >> 4) * 8;
  unsigned short* ph = Fhi + ((size_t)fid << 9) + lane * 8;
  unsigned short* pl = Flo + ((size_t)fid << 9) + lane * 8;
#pragma unroll
  for (int j = 0; j < 8; ++j){
    const float v = src[(size_t)(r0 + j) * 64 + col];
    const unsigned short h = f2bf(v);
    ph[j] = h;
    pl[j] = f2bf(v - bf2f(h));
  }
}

// ---------------- degree count (int) ----------------
__global__ __launch_bounds__(256) void k_cnt(const int* __restrict__ ht,
                                             int* __restrict__ cnti, int M)
{
  int m = blockIdx.x * 256 + threadIdx.x;
  if (m < M){
    atomicAdd(&cnti[ht[2*m+1]], 1);
    atomicAdd(&cnti[ht[2*m+0]], 1);
  }
}

// ---------------- exclusive prefix scan over cnti (one block) ----------------
__global__ __launch_bounds__(256) void k_scan(const int* __restrict__ cnti,
    int* __restrict__ pos, int N)
{
  __shared__ int ws[4];
  const int tid = threadIdx.x, lane = tid & 63, w = tid >> 6;
  const int chunk = (N + 255) / 256;
  int s = 0;
  for (int i = 0; i < chunk; ++i){ int idx = tid * chunk + i; if (idx < N) s += cnti[idx]; }
  int v = s;
#pragma unroll
  for (int off = 1; off < 64; off <<= 1){ int t = __shfl_up(v, off, 64); if (lane >= off) v += t; }
  if (lane == 63) ws[w] = v;
  __syncthreads();
  int wbase = 0;
  for (int i = 0; i < w; ++i) wbase += ws[i];
  int run = wbase + v - s;
  for (int i = 0; i < chunk; ++i){
    int idx = tid * chunk + i;
    if (idx < N){ int t = cnti[idx]; pos[idx] = run; run += t; }
  }
}

// ---------------- slot scatter: counting sort of 2M messages by dst ----------------
// slot j<M: mf for edge j (src=head, dst=tail); j>=M: mb for edge j-M (src=tail, dst=head)
__global__ __launch_bounds__(256) void k_slot(const int* __restrict__ ht,
    int* __restrict__ pos, int* __restrict__ order, int M)
{
  const int j = blockIdx.x * 256 + threadIdx.x;
  if (j < 2 * M){
    const int dst = (j < M) ? ht[2*j+1] : ht[2*(j-M)];
    const int slot = atomicAdd(&pos[dst], 1);
    order[slot] = j;
  }
}

// ---------------- sorted aggregation (MFMA, split bf16, segmented reduce) --------
// Block = 64 sorted slots. A = [H[src] | E] (64x128). Compute A@Wf and A@Wb,
// select per row by type, LDS-transpose, run-length sum over equal-dst rows,
// one atomicAdd per segment piece.
__global__ __launch_bounds__(256) void k_agg(
    const float* __restrict__ H, const float* __restrict__ Esrc,
    const float* __restrict__ E0t, const int* __restrict__ rt,
    const int* __restrict__ ht, const int* __restrict__ order,
    const unsigned short* __restrict__ Fhi, const unsigned short* __restrict__ Flo,
    const float* __restrict__ bf, const float* __restrict__ bb,
    float* __restrict__ agg, int M, int l0, int fbf, int fbb)
{
  __shared__ unsigned short Ahi[64 * 128];
  __shared__ unsigned short Alo[64 * 128];
  __shared__ float P[64 * 68];
  __shared__ int dsts[64];
  __shared__ int tpf[64];
  const int tile = blockIdx.x * 64;
  const int tid = threadIdx.x;
  const int M2 = 2 * M;

  // ---- stage 64 rows x 32 float4-chunks ----
#pragma unroll
  for (int i = 0; i < 8; ++i){
    const int idx = tid + 256 * i;
    const int row = idx >> 5, c = idx & 31;
    int s = tile + row;
    const bool oob = (s >= M2); if (oob) s = 0;
    const int j = order[s];
    const int fwd = (j < M) ? 1 : 0;
    const int e = fwd ? j : j - M;
    const int src = fwd ? ht[2*e] : ht[2*e+1];
    if (c == 0){
      dsts[row] = oob ? -1 : (fwd ? ht[2*e+1] : ht[2*e]);
      tpf[row] = fwd;
    }
    float4 a;
    if (c < 16) a = *(const float4*)&H[(size_t)src * 64 + (c & 15) * 4];
    else        a = l0 ? *(const float4*)&E0t[(size_t)rt[e] * 64 + (c & 15) * 4]
                       : *(const float4*)&Esrc[(size_t)e * 64 + (c & 15) * 4];
    ushort4 hi, lo; split4(a, hi, lo);
    const int ad = (row * 256 + c * 8) ^ ((row & 7) << 4);
    *(ushort4*)((char*)Ahi + ad) = hi;
    *(ushort4*)((char*)Alo + ad) = lo;
  }
  __syncthreads();

  const int w = tid >> 6, lane = tid & 63;
  const int g = lane >> 4, lr = lane & 15;
  const int rowb = w * 16;

  bf16x8 Ah[4], Al[4];
#pragma unroll
  for (int kt = 0; kt < 4; ++kt){
    const int row = rowb + lr;
    const int ad = (row * 256 + kt * 64 + g * 16) ^ ((row & 7) << 4);
    Ah[kt] = *(const bf16x8*)((const char*)Ahi + ad);
    Al[kt] = *(const bf16x8*)((const char*)Alo + ad);
  }

  f32x4 af[4], ab[4];
#pragma unroll
  for (int n = 0; n < 4; ++n){
    const float bvf = bf[n * 16 + lr], bvb = bb[n * 16 + lr];
    af[n] = (f32x4){bvf, bvf, bvf, bvf};
    ab[n] = (f32x4){bvb, bvb, bvb, bvb};
  }
#pragma unroll
  for (int n = 0; n < 4; ++n)
#pragma unroll
    for (int kt = 0; kt < 4; ++kt){
      const size_t ff = (((size_t)(fbf + kt * 4 + n)) << 9) + lane * 8;
      const bf16x8 whf = *(const bf16x8*)(Fhi + ff);
      const bf16x8 wlf = *(const bf16x8*)(Flo + ff);
      af[n] = __builtin_amdgcn_mfma_f32_16x16x32_bf16(Ah[kt], whf, af[n], 0, 0, 0);
      af[n] = __builtin_amdgcn_mfma_f32_16x16x32_bf16(Al[kt], whf, af[n], 0, 0, 0);
      af[n] = __builtin_amdgcn_mfma_f32_16x16x32_bf16(Ah[kt], wlf, af[n], 0, 0, 0);
      const size_t fbo = (((size_t)(fbb + kt * 4 + n)) << 9) + lane * 8;
      const bf16x8 whb = *(const bf16x8*)(Fhi + fbo);
      const bf16x8 wlb = *(const bf16x8*)(Flo + fbo);
      ab[n] = __builtin_amdgcn_mfma_f32_16x16x32_bf16(Ah[kt], whb, ab[n], 0, 0, 0);
      ab[n] = __builtin_amdgcn_mfma_f32_16x16x32_bf16(Al[kt], whb, ab[n], 0, 0, 0);
      ab[n] = __builtin_amdgcn_mfma_f32_16x16x32_bf16(Ah[kt], wlb, ab[n], 0, 0, 0);
    }

  // ---- select by type, transpose through LDS (wave-local rows) ----
#pragma unroll
  for (int n = 0; n < 4; ++n)
#pragma unroll
    for (int reg = 0; reg < 4; ++reg){
      const int row = rowb + g * 4 + reg;
      const float v = tpf[row] ? af[n][reg] : ab[n][reg];
      P[row * 68 + n * 16 + lr] = v;
    }

  // ---- run-length segmented sum over this wave's 16 rows, lane = col ----
  float run = 0.f;
  int cur = dsts[rowb];
  for (int r = 0; r < 16; ++r){
    const int row = rowb + r;
    const int dr = dsts[row];
    const float v = P[row * 68 + lane];
    if (dr != cur){
      if (cur >= 0) atomicAdd(&agg[(size_t)cur * 64 + lane], run);
      run = 0.f; cur = dr;
    }
    run += v;
  }
  if (cur >= 0) atomicAdd(&agg[(size_t)cur * 64 + lane], run);
}

// ---------------- edge update (MFMA, split bf16): Eout = LN(leaky(A@W+b)+E) ----------------
static __device__ __forceinline__ void stage_tile192(
    unsigned short* Ahi, unsigned short* Alo,
    const float* __restrict__ H, const float* __restrict__ Esrc,
    const float* __restrict__ E0t, const int* __restrict__ rt,
    const int* __restrict__ ht, int tile, int M, int l0, int tid)
{
#pragma unroll
  for (int i = 0; i < 12; ++i){
    const int idx = tid + 256 * i;
    const int row = idx / 48, c = idx % 48;
    int m = tile + row; if (m >= M) m = 0;
    const int h = ht[2*m], t = ht[2*m+1];
    const int cc = c & 15;
    float4 a;
    if (c < 16)      a = *(const float4*)&H[(size_t)h * 64 + cc * 4];
    else if (c < 32) a = l0 ? *(const float4*)&E0t[(size_t)rt[m] * 64 + cc * 4]
                            : *(const float4*)&Esrc[(size_t)m * 64 + cc * 4];
    else             a = *(const float4*)&H[(size_t)t * 64 + cc * 4];
    ushort4 hi, lo; split4(a, hi, lo);
    const int ad = (row * 384 + c * 8) ^ ((row & 7) << 4);
    *(ushort4*)((char*)Ahi + ad) = hi;
    *(ushort4*)((char*)Alo + ad) = lo;
  }
}

__global__ __launch_bounds__(256) void k_eu(
    const float* __restrict__ H, const float* __restrict__ Esrc,
    const float* __restrict__ E0t, const int* __restrict__ rt,
    const int* __restrict__ ht,
    const unsigned short* __restrict__ Fhi, const unsigned short* __restrict__ Flo, int fb,
    const float* __restrict__ b, const float* __restrict__ g_,
    const float* __restrict__ be, float* __restrict__ Eout, int M, int l0)
{
  __shared__ unsigned short Ahi[64 * 192];
  __shared__ unsigned short Alo[64 * 192];
  const int tile = blockIdx.x * 64;
  const int tid = threadIdx.x;
  stage_tile192(Ahi, Alo, H, Esrc, E0t, rt, ht, tile, M, l0, tid);
  __syncthreads();

  const int w = tid >> 6, lane = tid & 63;
  const int g = lane >> 4, lr = lane & 15;
  const int rowb = w * 16;

  bf16x8 Ah[6], Al[6];
#pragma unroll
  for (int kt = 0; kt < 6; ++kt){
    const int row = rowb + lr;
    const int ad = (row * 384 + kt * 64 + g * 16) ^ ((row & 7) << 4);
    Ah[kt] = *(const bf16x8*)((const char*)Ahi + ad);
    Al[kt] = *(const bf16x8*)((const char*)Alo + ad);
  }

  f32x4 acc[4];
#pragma unroll
  for (int n = 0; n < 4; ++n){
    const float bv = b[n * 16 + lr];
    acc[n] = (f32x4){bv, bv, bv, bv};
  }
#pragma unroll
  for (int n = 0; n < 4; ++n)
#pragma unroll
    for (int kt = 0; kt < 6; ++kt){
      const size_t fo = (((size_t)(fb + kt * 4 + n)) << 9) + lane * 8;
      const bf16x8 wh = *(const bf16x8*)(Fhi + fo);
      const bf16x8 wl = *(const bf16x8*)(Flo + fo);
      acc[n] = __builtin_amdgcn_mfma_f32_16x16x32_bf16(Ah[kt], wh, acc[n], 0, 0, 0);
      acc[n] = __builtin_amdgcn_mfma_f32_16x16x32_bf16(Al[kt], wh, acc[n], 0, 0, 0);
      acc[n] = __builtin_amdgcn_mfma_f32_16x16x32_bf16(Ah[kt], wl, acc[n], 0, 0, 0);
    }

#pragma unroll
  for (int reg = 0; reg < 4; ++reg){
    const int lrow = rowb + g * 4 + reg;
    float v[4];
#pragma unroll
    for (int n = 0; n < 4; ++n){
      const int col = n * 16 + lr;
      const int ad2 = (lrow * 384 + 128 + 2 * col) ^ ((lrow & 7) << 4);
      const float ep = bf2f(*(const unsigned short*)((const char*)Ahi + ad2))
                     + bf2f(*(const unsigned short*)((const char*)Alo + ad2));
      v[n] = leaky_(acc[n][reg]) + ep;
    }
    float s = v[0] + v[1] + v[2] + v[3];
#pragma unroll
    for (int msk = 1; msk < 16; msk <<= 1) s += __shfl_xor(s, msk, 64);
    const float mu = s * 0.015625f;
    float q = 0.f;
#pragma unroll
    for (int n = 0; n < 4; ++n){ v[n] -= mu; q += v[n] * v[n]; }
#pragma unroll
    for (int msk = 1; msk < 16; msk <<= 1) q += __shfl_xor(q, msk, 64);
    const float rs = rsqrtf(q * 0.015625f + 1e-5f);
    const int e = tile + lrow;
    if (e < M){
#pragma unroll
      for (int n = 0; n < 4; ++n){
        const int col = n * 16 + lr;
        Eout[(size_t)e * 64 + col] = v[n] * rs * g_[col] + be[col];
      }
    }
  }
}

// ---------------- f32 kernels ----------------
__global__ __launch_bounds__(256) void k_enc(const float* __restrict__ X,
    const float* __restrict__ W, const float* __restrict__ b,
    const float* __restrict__ g, const float* __restrict__ be,
    float* __restrict__ o0, float* __restrict__ o1, int nrows)
{
  const int w = threadIdx.x >> 6, d = threadIdx.x & 63;
  const int rbase = blockIdx.x * 16 + w * 4;
  int rows[4];
#pragma unroll
  for (int j = 0; j < 4; ++j){ int r = rbase + j; rows[j] = r < nrows ? r : nrows - 1; }
  float acc[4] = {0.f, 0.f, 0.f, 0.f};
  for (int k4 = 0; k4 < IN_DIM / 4; ++k4){
    const int k = k4 * 4;
    const float w0 = W[(k+0)*64+d], w1 = W[(k+1)*64+d];
    const float w2 = W[(k+2)*64+d], w3 = W[(k+3)*64+d];
#pragma unroll
    for (int j = 0; j < 4; ++j){
      const float4 a = *(const float4*)&X[(size_t)rows[j] * IN_DIM + k];
      acc[j] = fmaf(a.x, w0, fmaf(a.y, w1, fmaf(a.z, w2, fmaf(a.w, w3, acc[j]))));
    }
  }
#pragma unroll
  for (int j = 0; j < 4; ++j){
    const int r = rbase + j;
    if (r < nrows){
      float v = wln_(leaky_(acc[j] + b[d]), g[d], be[d]);
      o0[(size_t)r*64+d] = v;
      if (o1) o1[(size_t)r*64+d] = v;
    }
  }
}

__global__ __launch_bounds__(256) void k_hupd(float* __restrict__ H,
    const float* __restrict__ agg, const int* __restrict__ cnti,
    const float* __restrict__ g, const float* __restrict__ be, int N)
{
  const int w = threadIdx.x >> 6, d = threadIdx.x & 63;
  const int n = blockIdx.x * 4 + w;
  if (n >= N) return;
  const float c = (float)cnti[n];
  const float a = agg[(size_t)n*64+d] / c;
  const float v = leaky_(a) + H[(size_t)n*64+d];
  H[(size_t)n*64+d] = wln_(v, g[d], be[d]);
}

__global__ __launch_bounds__(256) void k_qcount(const int* __restrict__ q,
                                                int* __restrict__ bcnt, int M)
{
  const int j = blockIdx.x * 256 + threadIdx.x;
  const int have = (j < M) && (q[j] != 0);
  unsigned long long bal = __ballot(have);
  if ((threadIdx.x & 63) == 0) atomicAdd(&bcnt[blockIdx.x], (int)__popcll(bal));
}

__global__ __launch_bounds__(256) void k_qscan(int* __restrict__ bcnt, int nb)
{
  __shared__ int ws[4];
  const int tid = threadIdx.x, lane = tid & 63, w = tid >> 6;
  const int chunk = (nb + 255) / 256;
  int s = 0;
  for (int i = 0; i < chunk; ++i){ int idx = tid * chunk + i; if (idx < nb) s += bcnt[idx]; }
  int v = s;
#pragma unroll
  for (int off = 1; off < 64; off <<= 1){ int t = __shfl_up(v, off, 64); if (lane >= off) v += t; }
  if (lane == 63) ws[w] = v;
  __syncthreads();
  int wbase = 0;
  for (int i = 0; i < w; ++i) wbase += ws[i];
  int run = wbase + v - s;
  for (int i = 0; i < chunk; ++i){
    int idx = tid * chunk + i;
    if (idx < nb){ int t = bcnt[idx]; bcnt[idx] = run; run += t; }
  }
}

__global__ __launch_bounds__(256) void k_qemit(const int* __restrict__ q,
    const int* __restrict__ bcnt, int* __restrict__ qi, int M, int NQ)
{
  __shared__ int wb[4];
  const int j = blockIdx.x * 256 + threadIdx.x;
  const int lane = threadIdx.x & 63, w = threadIdx.x >> 6;
  const int have = (j < M) && (q[j] != 0);
  unsigned long long bal = __ballot(have);
  if (lane == 0) wb[w] = (int)__popcll(bal);
  __syncthreads();
  int base = bcnt[blockIdx.x];
  for (int i = 0; i < w; ++i) base += wb[i];
  const int rank = base + (int)__popcll(bal & ((1ull << lane) - 1ull));
  if (have && rank < NQ) qi[rank] = j;
}

__global__ __launch_bounds__(256) void k_feat(
    const float* __restrict__ H, const float* __restrict__ H0,
    const float* __restrict__ E1, const float* __restrict__ E0t,
    const int* __restrict__ rt, const int* __restrict__ ht, const int* __restrict__ qi,
    const float* __restrict__ W, const float* __restrict__ b,
    const float* __restrict__ g, const float* __restrict__ be,
    float* __restrict__ feat, int NQ)
{
  const int w = threadIdx.x >> 6, d = threadIdx.x & 63;
  const int row = blockIdx.x * 4 + w;
  if (row >= NQ) return;
  const int m = qi[row];
  const int h = ht[2*m], t = ht[2*m+1], r = rt[m];
  const float* seg0 = H  + (size_t)h * 64;
  const float* seg1 = E1 + (size_t)m * 64;
  const float* seg2 = H  + (size_t)t * 64;
  float acc = b[d];
  for (int k4 = 0; k4 < 48; ++k4){
    const int k = k4 * 4;
    const float* A = (k4 < 16) ? seg0 : (k4 < 32) ? seg1 - 64 : seg2 - 128;
    const float4 a = *(const float4*)&A[k];
    acc = fmaf(a.x, W[(k+0)*64+d], fmaf(a.y, W[(k+1)*64+d],
          fmaf(a.z, W[(k+2)*64+d], fmaf(a.w, W[(k+3)*64+d], acc))));
  }
  const float ep = E1[(size_t)m*64+d];
  const float e2 = wln_(leaky_(acc) + ep, g[d], be[d]);
  float* F = feat + (size_t)row * 384;
  F[      d] = e2;
  F[ 64 + d] = E0t[(size_t)r*64+d];
  F[128 + d] = H [(size_t)h*64+d];
  F[192 + d] = H0[(size_t)h*64+d];
  F[256 + d] = H [(size_t)t*64+d];
  F[320 + d] = H0[(size_t)t*64+d];
}

__global__ __launch_bounds__(256) void k_cls(const float* __restrict__ feat,
    const float* __restrict__ W1, const float* __restrict__ b1,
    const float* __restrict__ W2, const float* __restrict__ b2,
    float* __restrict__ out, int NQ)
{
  const int w = threadIdx.x >> 6, d = threadIdx.x & 63;
  const int row = blockIdx.x * 4 + w;
  if (row >= NQ) return;
  const float* F = feat + (size_t)row * 384;
  float acc = b1[d];
  for (int k4 = 0; k4 < 96; ++k4){
    const int k = k4 * 4;
    const float4 a = *(const float4*)&F[k];
    acc = fmaf(a.x, W1[(k+0)*64+d], fmaf(a.y, W1[(k+1)*64+d],
          fmaf(a.z, W1[(k+2)*64+d], fmaf(a.w, W1[(k+3)*64+d], acc))));
  }
  float hs = leaky_(acc) * W2[d];
  hs = wsum_(hs);
  if (d == 0) out[row] = hs + b2[0];
}

extern "C" void kernel_launch(void* const* d_in, const int* in_sizes, int n_in,
                              void* d_out, int out_size, void* d_ws, size_t ws_size,
                              hipStream_t stream)
{
  const int*   ht    = (const int*)  d_in[0];
  const int*   rt    = (const int*)  d_in[1];
  const float* ef    = (const float*)d_in[2];
  const int*   q     = (const int*)  d_in[3];
  const float* rtab  = (const float*)d_in[4];
  const float* W_ent = (const float*)d_in[5];
  const float* b_ent = (const float*)d_in[6];
  const float* g_ent = (const float*)d_in[7];
  const float* be_ent= (const float*)d_in[8];
  const float* W_ein = (const float*)d_in[9];
  const float* b_ein = (const float*)d_in[10];
  const float* g_e   = (const float*)d_in[11];
  const float* be_e  = (const float*)d_in[12];
  const float* mp_Wf = (const float*)d_in[13];
  const float* mp_bf = (const float*)d_in[14];
  const float* mp_Wb = (const float*)d_in[15];
  const float* mp_bb = (const float*)d_in[16];
  const float* mp_g  = (const float*)d_in[17];
  const float* mp_be = (const float*)d_in[18];
  const float* eu_W  = (const float*)d_in[19];
  const float* eu_b  = (const float*)d_in[20];
  const float* eu_g  = (const float*)d_in[21];
  const float* eu_be = (const float*)d_in[22];
  const float* clsW1 = (const float*)d_in[23];
  const float* clsb1 = (const float*)d_in[24];
  const float* clsW2 = (const float*)d_in[25];
  const float* clsb2 = (const float*)d_in[26];

  const int M    = in_sizes[1];
  const int N    = in_sizes[2] / IN_DIM;
  const int NREL = in_sizes[4] / IN_DIM;
  const int NQ   = out_size;
  const int nb   = (M + 255) / 256;

  unsigned short* Fhi = (unsigned short*)d_ws;
  unsigned short* Flo = Fhi + 88 * 512;
  float* H0   = (float*)(Fhi + 2 * 88 * 512);
  float* H    = H0   + (size_t)N * 64;
  float* agg  = H    + (size_t)N * 64;
  float* E1   = agg  + (size_t)N * 64;
  float* E0t  = E1   + (size_t)M * 64;
  float* feat = E0t  + (size_t)NREL * 64;
  int*   cnti = (int*)(feat + (size_t)NQ * 384);
  int*   pos  = cnti + N;
  int*   order= pos  + N;
  int*   qi   = order + 2 * (size_t)M;
  int*   bcnt = qi + NQ;

  hipMemsetAsync(cnti, 0, (size_t)N  * 4, stream);
  hipMemsetAsync(qi,   0, (size_t)NQ * 4, stream);
  hipMemsetAsync(bcnt, 0, (size_t)nb * 4, stream);

  k_wprep<<<22, 256, 0, stream>>>(mp_Wf, mp_Wb, eu_W, Fhi, Flo);
  k_enc<<<(N + 15) / 16, 256, 0, stream>>>(ef, W_ent, b_ent, g_ent, be_ent, H0, H, N);
  k_enc<<<(NREL + 15) / 16, 256, 0, stream>>>(rtab, W_ein, b_ein, g_e, be_e, E0t, nullptr, NREL);
  k_cnt<<<(M + 255) / 256, 256, 0, stream>>>(ht, cnti, M);
  k_scan<<<1, 256, 0, stream>>>(cnti, pos, N);
  k_slot<<<(2 * M + 255) / 256, 256, 0, stream>>>(ht, pos, order, M);

  const int atiles = (2 * M + 63) / 64;
  const int etiles = (M + 63) / 64;
  // ---- layer 0 ----
  hipMemsetAsync(agg, 0, (size_t)N * 64 * 4, stream);
  k_agg<<<atiles, 256, 0, stream>>>(H, E1, E0t, rt, ht, order, Fhi, Flo,
      mp_bf + 0, mp_bb + 0, agg, M, 1, 0, 16);
  k_hupd<<<(N + 3) / 4, 256, 0, stream>>>(H, agg, cnti, mp_g + 0, mp_be + 0, N);
  k_eu<<<etiles, 256, 0, stream>>>(H, E1, E0t, rt, ht, Fhi, Flo, 64,
      eu_b + 0, eu_g + 0, eu_be + 0, E1, M, 1);
  // ---- layer 1 ----
  hipMemsetAsync(agg, 0, (size_t)N * 64 * 4, stream);
  k_agg<<<atiles, 256, 0, stream>>>(H, E1, E0t, rt, ht, order, Fhi, Flo,
      mp_bf + 64, mp_bb + 64, agg, M, 0, 32, 48);
  k_hupd<<<(N + 3) / 4, 256, 0, stream>>>(H, agg, cnti, mp_g + 64, mp_be + 64, N);

  // qi compaction
  k_qcount<<<nb, 256, 0, stream>>>(q, bcnt, M);
  k_qscan<<<1, 256, 0, stream>>>(bcnt, nb);
  k_qemit<<<nb, 256, 0, stream>>>(q, bcnt, qi, M, NQ);

  // features + classifier
  k_feat<<<(NQ + 3) / 4, 256, 0, stream>>>(H, H0, E1, E0t, rt, ht, qi,
      eu_W + 192*64, eu_b + 64, eu_g + 64, eu_be + 64, feat, NQ);
  k_cls<<<(NQ + 3) / 4, 256, 0, stream>>>(feat, clsW1, clsb1, clsW2, clsb2,
      (float*)d_out, NQ);
}

// Round 5
// 1507.290 us; speedup vs baseline: 1.5321x; 1.5321x over previous
//
#include <hip/hip_runtime.h>
#include <cstdint>

constexpr int IN_DIM = 768;

static __device__ __forceinline__ float leaky_(float x){ return x >= 0.0f ? x : 0.01f * x; }

static __device__ __forceinline__ float wsum_(float v){
#pragma unroll
  for (int m = 1; m < 64; m <<= 1) v += __shfl_xor(v, m, 64);
  return v;
}

static __device__ __forceinline__ float wln_(float v, float g, float be){
  float mu  = wsum_(v) * 0.015625f;
  float c   = v - mu;
  float var = wsum_(c * c) * 0.015625f;
  return c * rsqrtf(var + 1e-5f) * g + be;
}

// Encoder: out = LN(leaky(X @ W + b)) for (nrows, 768) @ (768, 64).
__global__ __launch_bounds__(256) void k_enc(const float* __restrict__ X,
    const float* __restrict__ W, const float* __restrict__ b,
    const float* __restrict__ g, const float* __restrict__ be,
    float* __restrict__ o0, float* __restrict__ o1, int nrows)
{
  const int w = threadIdx.x >> 6, d = threadIdx.x & 63;
  const int rbase = blockIdx.x * 16 + w * 4;
  int rows[4];
#pragma unroll
  for (int j = 0; j < 4; ++j){ int r = rbase + j; rows[j] = r < nrows ? r : nrows - 1; }
  float acc[4] = {0.f, 0.f, 0.f, 0.f};
  for (int k4 = 0; k4 < IN_DIM / 4; ++k4){
    const int k = k4 * 4;
    const float w0 = W[(k+0)*64+d], w1 = W[(k+1)*64+d];
    const float w2 = W[(k+2)*64+d], w3 = W[(k+3)*64+d];
#pragma unroll
    for (int j = 0; j < 4; ++j){
      const float4 a = *(const float4*)&X[(size_t)rows[j] * IN_DIM + k];
      acc[j] = fmaf(a.x, w0, fmaf(a.y, w1, fmaf(a.z, w2, fmaf(a.w, w3, acc[j]))));
    }
  }
#pragma unroll
  for (int j = 0; j < 4; ++j){
    const int r = rbase + j;
    if (r < nrows){
      float v = wln_(leaky_(acc[j] + b[d]), g[d], be[d]);
      o0[(size_t)r*64+d] = v;
      if (o1) o1[(size_t)r*64+d] = v;
    }
  }
}

// Generic small matmul: Y = X(nrows x 64) @ W(64 x 64) [+ bias]
__global__ __launch_bounds__(256) void k_xw(const float* __restrict__ X,
    const float* __restrict__ W, const float* __restrict__ bias,
    float* __restrict__ Y, int nrows)
{
  const int w = threadIdx.x >> 6, d = threadIdx.x & 63;
  const int rbase = blockIdx.x * 16 + w * 4;
  int rows[4];
#pragma unroll
  for (int j = 0; j < 4; ++j){ int r = rbase + j; rows[j] = r < nrows ? r : nrows - 1; }
  const float b0 = bias ? bias[d] : 0.f;
  float acc[4] = {b0, b0, b0, b0};
  for (int k4 = 0; k4 < 16; ++k4){
    const int k = k4 * 4;
    const float w0 = W[(k+0)*64+d], w1 = W[(k+1)*64+d];
    const float w2 = W[(k+2)*64+d], w3 = W[(k+3)*64+d];
#pragma unroll
    for (int j = 0; j < 4; ++j){
      const float4 a = *(const float4*)&X[(size_t)rows[j] * 64 + k];
      acc[j] = fmaf(a.x, w0, fmaf(a.y, w1, fmaf(a.z, w2, fmaf(a.w, w3, acc[j]))));
    }
  }
#pragma unroll
  for (int j = 0; j < 4; ++j){
    const int r = rbase + j;
    if (r < nrows) Y[(size_t)r*64+d] = acc[j];
  }
}

// Degree counts: cf[n] = #(tail==n) (fwd msgs), cb[n] = #(head==n) (bwd msgs)
__global__ __launch_bounds__(256) void k_cnt(const int* __restrict__ ht,
    int* __restrict__ cf, int* __restrict__ cb, int M)
{
  int m = blockIdx.x * 256 + threadIdx.x;
  if (m < M){
    atomicAdd(&cf[ht[2*m+1]], 1);
    atomicAdd(&cb[ht[2*m+0]], 1);
  }
}

// Exclusive prefix scan over cf+cb (one block) -> pos (slot cursor)
__global__ __launch_bounds__(256) void k_scan(const int* __restrict__ cf,
    const int* __restrict__ cb, int* __restrict__ pos, int N)
{
  __shared__ int ws[4];
  const int tid = threadIdx.x, lane = tid & 63, w = tid >> 6;
  const int chunk = (N + 255) / 256;
  int s = 0;
  for (int i = 0; i < chunk; ++i){ int idx = tid * chunk + i; if (idx < N) s += cf[idx] + cb[idx]; }
  int v = s;
#pragma unroll
  for (int off = 1; off < 64; off <<= 1){ int t = __shfl_up(v, off, 64); if (lane >= off) v += t; }
  if (lane == 63) ws[w] = v;
  __syncthreads();
  int wbase = 0;
  for (int i = 0; i < w; ++i) wbase += ws[i];
  int run = wbase + v - s;
  for (int i = 0; i < chunk; ++i){
    int idx = tid * chunk + i;
    if (idx < N){ int t = cf[idx] + cb[idx]; pos[idx] = run; run += t; }
  }
}

// Counting-sort scatter (CSR build). slot arrays:
// srcf[slot] = src_node | (fwd << 31); er[slot] = edge idx; rr[slot] = rt[edge].
__global__ __launch_bounds__(256) void k_slot(const int* __restrict__ ht,
    const int* __restrict__ rt, int* __restrict__ pos,
    int* __restrict__ srcf, int* __restrict__ er, int* __restrict__ rr, int M)
{
  const int j = blockIdx.x * 256 + threadIdx.x;
  if (j < 2 * M){
    const int fwd = (j < M) ? 1 : 0;
    const int e = fwd ? j : j - M;
    const int dst = fwd ? ht[2*e+1] : ht[2*e];
    const int src = fwd ? ht[2*e]   : ht[2*e+1];
    const int slot = atomicAdd(&pos[dst], 1);
    srcf[slot] = src | (fwd << 31);
    er[slot] = e;
    rr[slot] = rt[e];
  }
}

// CSR pull-sum: per node n (one wave, lane=col):
//   S_f = sum_{fwd slots} H[src], SE_f = sum E[erow], same for bwd.
// Sall[n] = [S_f | SE_f | S_b | SE_b] (256 floats). No LDS, no atomics.
__global__ __launch_bounds__(256) void k_sum(const float* __restrict__ H,
    const float* __restrict__ E, const int* __restrict__ srcf,
    const int* __restrict__ eidx, const int* __restrict__ pos_end,
    const int* __restrict__ cf, const int* __restrict__ cb,
    float* __restrict__ Sall, int N)
{
  const int w = threadIdx.x >> 6, lane = threadIdx.x & 63;
  const int n = blockIdx.x * 4 + w;
  if (n >= N) return;
  const int end = pos_end[n];
  const int start = end - (cf[n] + cb[n]);
  float sf = 0.f, ef = 0.f, sb = 0.f, eb = 0.f;
#pragma unroll 4
  for (int i = start; i < end; ++i){
    const unsigned u = (unsigned)srcf[i];
    const int src = (int)(u & 0x7fffffffu);
    const int ev  = eidx[i];
    const float h = H[(size_t)src * 64 + lane];
    const float e = E[(size_t)ev  * 64 + lane];
    if (u >> 31){ sf += h; ef += e; }
    else        { sb += h; eb += e; }
  }
  float* S = Sall + (size_t)n * 256;
  S[       lane] = sf;
  S[ 64 + lane] = ef;
  S[128 + lane] = sb;
  S[192 + lane] = eb;
}

// Dense post-aggregation update:
// agg = Sall @ [Wf ; Wb] + cf*bf + cb*bb ; H = LN(leaky(agg/cnt) + H)
__global__ __launch_bounds__(256) void k_hupd2(float* __restrict__ H,
    const float* __restrict__ Sall, const int* __restrict__ cf, const int* __restrict__ cb,
    const float* __restrict__ Wf, const float* __restrict__ Wb,
    const float* __restrict__ bf, const float* __restrict__ bb,
    const float* __restrict__ g, const float* __restrict__ be, int N)
{
  const int w = threadIdx.x >> 6, d = threadIdx.x & 63;
  const int rbase = blockIdx.x * 16 + w * 4;
  int rows[4];
#pragma unroll
  for (int j = 0; j < 4; ++j){ int r = rbase + j; rows[j] = r < N ? r : N - 1; }
  float acc[4];
#pragma unroll
  for (int j = 0; j < 4; ++j)
    acc[j] = (float)cf[rows[j]] * bf[d] + (float)cb[rows[j]] * bb[d];
  for (int k4 = 0; k4 < 64; ++k4){
    const int k = k4 * 4;
    const float* Wsel = (k < 128) ? (Wf + k * 64) : (Wb + (k - 128) * 64);
    const float w0 = Wsel[0*64+d], w1 = Wsel[1*64+d];
    const float w2 = Wsel[2*64+d], w3 = Wsel[3*64+d];
#pragma unroll
    for (int j = 0; j < 4; ++j){
      const float4 a = *(const float4*)&Sall[(size_t)rows[j] * 256 + k];
      acc[j] = fmaf(a.x, w0, fmaf(a.y, w1, fmaf(a.z, w2, fmaf(a.w, w3, acc[j]))));
    }
  }
#pragma unroll
  for (int j = 0; j < 4; ++j){
    const int r = rbase + j;
    if (r < N){
      const float c = (float)(cf[r] + cb[r]);
      const float v = leaky_(acc[j] / c) + H[(size_t)r*64+d];
      H[(size_t)r*64+d] = wln_(v, g[d], be[d]);
    }
  }
}

// Layer-0 edge update, decomposed: E1[m] = LN(leaky(HW1[h]+TE[rt]+HW3[t]) + E0t[rt])
__global__ __launch_bounds__(256) void k_eu2(const float* __restrict__ HW1,
    const float* __restrict__ HW3, const float* __restrict__ TE,
    const float* __restrict__ E0t, const int* __restrict__ ht,
    const int* __restrict__ rt, const float* __restrict__ g,
    const float* __restrict__ be, float* __restrict__ E1, int M)
{
  const int w = threadIdx.x >> 6, lane = threadIdx.x & 63;
  const int m = blockIdx.x * 4 + w;
  if (m >= M) return;
  const int h = ht[2*m], t = ht[2*m+1], r = rt[m];
  float v = HW1[(size_t)h*64+lane] + HW3[(size_t)t*64+lane] + TE[(size_t)r*64+lane];
  v = leaky_(v) + E0t[(size_t)r*64+lane];
  E1[(size_t)m*64+lane] = wln_(v, g[lane], be[lane]);
}

// ---- qi = nonzero(queries) compaction ----
__global__ __launch_bounds__(256) void k_qcount(const int* __restrict__ q,
                                                int* __restrict__ bcnt, int M)
{
  const int j = blockIdx.x * 256 + threadIdx.x;
  const int have = (j < M) && (q[j] != 0);
  unsigned long long bal = __ballot(have);
  if ((threadIdx.x & 63) == 0) atomicAdd(&bcnt[blockIdx.x], (int)__popcll(bal));
}

__global__ __launch_bounds__(256) void k_qscan(int* __restrict__ bcnt, int nb)
{
  __shared__ int ws[4];
  const int tid = threadIdx.x, lane = tid & 63, w = tid >> 6;
  const int chunk = (nb + 255) / 256;
  int s = 0;
  for (int i = 0; i < chunk; ++i){ int idx = tid * chunk + i; if (idx < nb) s += bcnt[idx]; }
  int v = s;
#pragma unroll
  for (int off = 1; off < 64; off <<= 1){ int t = __shfl_up(v, off, 64); if (lane >= off) v += t; }
  if (lane == 63) ws[w] = v;
  __syncthreads();
  int wbase = 0;
  for (int i = 0; i < w; ++i) wbase += ws[i];
  int run = wbase + v - s;
  for (int i = 0; i < chunk; ++i){
    int idx = tid * chunk + i;
    if (idx < nb){ int t = bcnt[idx]; bcnt[idx] = run; run += t; }
  }
}

__global__ __launch_bounds__(256) void k_qemit(const int* __restrict__ q,
    const int* __restrict__ bcnt, int* __restrict__ qi, int M, int NQ)
{
  __shared__ int wb[4];
  const int j = blockIdx.x * 256 + threadIdx.x;
  const int lane = threadIdx.x & 63, w = threadIdx.x >> 6;
  const int have = (j < M) && (q[j] != 0);
  unsigned long long bal = __ballot(have);
  if (lane == 0) wb[w] = (int)__popcll(bal);
  __syncthreads();
  int base = bcnt[blockIdx.x];
  for (int i = 0; i < w; ++i) base += wb[i];
  const int rank = base + (int)__popcll(bal & ((1ull << lane) - 1ull));
  if (have && rank < NQ) qi[rank] = j;
}

// Layer-1 edge update for query rows only + feature assembly.
__global__ __launch_bounds__(256) void k_feat(
    const float* __restrict__ H, const float* __restrict__ H0,
    const float* __restrict__ E1, const float* __restrict__ E0t,
    const int* __restrict__ rt, const int* __restrict__ ht, const int* __restrict__ qi,
    const float* __restrict__ W, const float* __restrict__ b,
    const float* __restrict__ g, const float* __restrict__ be,
    float* __restrict__ feat, int NQ)
{
  const int w = threadIdx.x >> 6, d = threadIdx.x & 63;
  const int row = blockIdx.x * 4 + w;
  if (row >= NQ) return;
  const int m = qi[row];
  const int h = ht[2*m], t = ht[2*m+1], r = rt[m];
  const float* seg0 = H  + (size_t)h * 64;
  const float* seg1 = E1 + (size_t)m * 64;
  const float* seg2 = H  + (size_t)t * 64;
  float acc = b[d];
  for (int k4 = 0; k4 < 48; ++k4){
    const int k = k4 * 4;
    const float* A = (k4 < 16) ? seg0 : (k4 < 32) ? seg1 - 64 : seg2 - 128;
    const float4 a = *(const float4*)&A[k];
    acc = fmaf(a.x, W[(k+0)*64+d], fmaf(a.y, W[(k+1)*64+d],
          fmaf(a.z, W[(k+2)*64+d], fmaf(a.w, W[(k+3)*64+d], acc))));
  }
  const float ep = E1[(size_t)m*64+d];
  const float e2 = wln_(leaky_(acc) + ep, g[d], be[d]);
  float* F = feat + (size_t)row * 384;
  F[      d] = e2;
  F[ 64 + d] = E0t[(size_t)r*64+d];
  F[128 + d] = H [(size_t)h*64+d];
  F[192 + d] = H0[(size_t)h*64+d];
  F[256 + d] = H [(size_t)t*64+d];
  F[320 + d] = H0[(size_t)t*64+d];
}

__global__ __launch_bounds__(256) void k_cls(const float* __restrict__ feat,
    const float* __restrict__ W1, const float* __restrict__ b1,
    const float* __restrict__ W2, const float* __restrict__ b2,
    float* __restrict__ out, int NQ)
{
  const int w = threadIdx.x >> 6, d = threadIdx.x & 63;
  const int row = blockIdx.x * 4 + w;
  if (row >= NQ) return;
  const float* F = feat + (size_t)row * 384;
  float acc = b1[d];
  for (int k4 = 0; k4 < 96; ++k4){
    const int k = k4 * 4;
    const float4 a = *(const float4*)&F[k];
    acc = fmaf(a.x, W1[(k+0)*64+d], fmaf(a.y, W1[(k+1)*64+d],
          fmaf(a.z, W1[(k+2)*64+d], fmaf(a.w, W1[(k+3)*64+d], acc))));
  }
  float hs = leaky_(acc) * W2[d];
  hs = wsum_(hs);
  if (d == 0) out[row] = hs + b2[0];
}

extern "C" void kernel_launch(void* const* d_in, const int* in_sizes, int n_in,
                              void* d_out, int out_size, void* d_ws, size_t ws_size,
                              hipStream_t stream)
{
  const int*   ht    = (const int*)  d_in[0];
  const int*   rt    = (const int*)  d_in[1];
  const float* ef    = (const float*)d_in[2];
  const int*   q     = (const int*)  d_in[3];
  const float* rtab  = (const float*)d_in[4];
  const float* W_ent = (const float*)d_in[5];
  const float* b_ent = (const float*)d_in[6];
  const float* g_ent = (const float*)d_in[7];
  const float* be_ent= (const float*)d_in[8];
  const float* W_ein = (const float*)d_in[9];
  const float* b_ein = (const float*)d_in[10];
  const float* g_e   = (const float*)d_in[11];
  const float* be_e  = (const float*)d_in[12];
  const float* mp_Wf = (const float*)d_in[13];
  const float* mp_bf = (const float*)d_in[14];
  const float* mp_Wb = (const float*)d_in[15];
  const float* mp_bb = (const float*)d_in[16];
  const float* mp_g  = (const float*)d_in[17];
  const float* mp_be = (const float*)d_in[18];
  const float* eu_W  = (const float*)d_in[19];
  const float* eu_b  = (const float*)d_in[20];
  const float* eu_g  = (const float*)d_in[21];
  const float* eu_be = (const float*)d_in[22];
  const float* clsW1 = (const float*)d_in[23];
  const float* clsb1 = (const float*)d_in[24];
  const float* clsW2 = (const float*)d_in[25];
  const float* clsb2 = (const float*)d_in[26];

  const int M    = in_sizes[1];
  const int N    = in_sizes[2] / IN_DIM;
  const int NREL = in_sizes[4] / IN_DIM;
  const int NQ   = out_size;
  const int nb   = (M + 255) / 256;

  float* H0   = (float*)d_ws;
  float* H    = H0   + (size_t)N * 64;
  float* HW1  = H    + (size_t)N * 64;
  float* HW3  = HW1  + (size_t)N * 64;
  float* Sall = HW3  + (size_t)N * 64;
  float* E1   = Sall + (size_t)N * 256;
  float* E0t  = E1   + (size_t)M * 64;
  float* TE   = E0t  + (size_t)NREL * 64;
  float* feat = TE   + (size_t)NREL * 64;
  int*   cf   = (int*)(feat + (size_t)NQ * 384);
  int*   cb   = cf + N;
  int*   pos  = cb + N;
  int*   srcf = pos + N;
  int*   er   = srcf + 2 * (size_t)M;
  int*   rr   = er   + 2 * (size_t)M;
  int*   qi   = rr   + 2 * (size_t)M;
  int*   bcnt = qi + NQ;

  hipMemsetAsync(cf,   0, (size_t)N  * 4, stream);
  hipMemsetAsync(cb,   0, (size_t)N  * 4, stream);
  hipMemsetAsync(qi,   0, (size_t)NQ * 4, stream);
  hipMemsetAsync(bcnt, 0, (size_t)nb * 4, stream);

  // CSR build
  k_cnt<<<(M + 255) / 256, 256, 0, stream>>>(ht, cf, cb, M);
  k_scan<<<1, 256, 0, stream>>>(cf, cb, pos, N);
  k_slot<<<(2 * M + 255) / 256, 256, 0, stream>>>(ht, rt, pos, srcf, er, rr, M);

  // Encoders + eu layer-0 E-table
  k_enc<<<(N + 15) / 16, 256, 0, stream>>>(ef, W_ent, b_ent, g_ent, be_ent, H0, H, N);
  k_enc<<<(NREL + 15) / 16, 256, 0, stream>>>(rtab, W_ein, b_ein, g_e, be_e, E0t, nullptr, NREL);
  k_xw<<<(NREL + 15) / 16, 256, 0, stream>>>(E0t, eu_W + 64 * 64, eu_b, TE, NREL);

  // ---- layer 0 ----
  k_sum<<<(N + 3) / 4, 256, 0, stream>>>(H, E0t, srcf, rr, pos, cf, cb, Sall, N);
  k_hupd2<<<(N + 15) / 16, 256, 0, stream>>>(H, Sall, cf, cb,
      mp_Wf, mp_Wb, mp_bf, mp_bb, mp_g, mp_be, N);
  k_xw<<<(N + 15) / 16, 256, 0, stream>>>(H, eu_W, nullptr, HW1, N);
  k_xw<<<(N + 15) / 16, 256, 0, stream>>>(H, eu_W + 128 * 64, nullptr, HW3, N);
  k_eu2<<<(M + 3) / 4, 256, 0, stream>>>(HW1, HW3, TE, E0t, ht, rt, eu_g, eu_be, E1, M);

  // ---- layer 1 ----
  k_sum<<<(N + 3) / 4, 256, 0, stream>>>(H, E1, srcf, er, pos, cf, cb, Sall, N);
  k_hupd2<<<(N + 15) / 16, 256, 0, stream>>>(H, Sall, cf, cb,
      mp_Wf + 128 * 64, mp_Wb + 128 * 64, mp_bf + 64, mp_bb + 64,
      mp_g + 64, mp_be + 64, N);

  // qi compaction
  k_qcount<<<nb, 256, 0, stream>>>(q, bcnt, M);
  k_qscan<<<1, 256, 0, stream>>>(bcnt, nb);
  k_qemit<<<nb, 256, 0, stream>>>(q, bcnt, qi, M, NQ);

  // features + classifier (layer-1 edge update fused at query rows)
  k_feat<<<(NQ + 3) / 4, 256, 0, stream>>>(H, H0, E1, E0t, rt, ht, qi,
      eu_W + 192 * 64, eu_b + 64, eu_g + 64, eu_be + 64, feat, NQ);
  k_cls<<<(NQ + 3) / 4, 256, 0, stream>>>(feat, clsW1, clsb1, clsW2, clsb2,
      (float*)d_out, NQ);
}

// Round 7
// 1184.419 us; speedup vs baseline: 1.9498x; 1.2726x over previous
//
#include <hip/hip_runtime.h>
#include <hip/hip_bf16.h>
#include <cstdint>

constexpr int IN_DIM = 768;
constexpr int NFRAG  = 96;   // W_ent (768x64) -> 24 kt x 4 n

typedef __attribute__((ext_vector_type(8))) short bf16x8;
typedef __attribute__((ext_vector_type(4))) float f32x4;

static __device__ __forceinline__ float leaky_(float x){ return x >= 0.0f ? x : 0.01f * x; }

static __device__ __forceinline__ float wsum_(float v){
#pragma unroll
  for (int m = 1; m < 64; m <<= 1) v += __shfl_xor(v, m, 64);
  return v;
}

static __device__ __forceinline__ float wln_(float v, float g, float be){
  float mu  = wsum_(v) * 0.015625f;
  float c   = v - mu;
  float var = wsum_(c * c) * 0.015625f;
  return c * rsqrtf(var + 1e-5f) * g + be;
}

static __device__ __forceinline__ unsigned short f2bf(float x){
  return __bfloat16_as_ushort(__float2bfloat16(x));
}
static __device__ __forceinline__ float bf2f(unsigned short u){
  return __bfloat162float(__ushort_as_bfloat16(u));
}
static __device__ __forceinline__ void split4(const float4 a, ushort4& hi, ushort4& lo){
  hi.x = f2bf(a.x); lo.x = f2bf(a.x - bf2f(hi.x));
  hi.y = f2bf(a.y); lo.y = f2bf(a.y - bf2f(hi.y));
  hi.z = f2bf(a.z); lo.z = f2bf(a.z - bf2f(hi.z));
  hi.w = f2bf(a.w); lo.w = f2bf(a.w - bf2f(hi.w));
}

static __device__ __forceinline__ f32x4 mfma3(bf16x8 ah, bf16x8 al, bf16x8 wh, bf16x8 wl, f32x4 acc){
  acc = __builtin_amdgcn_mfma_f32_16x16x32_bf16(ah, wh, acc, 0, 0, 0);
  acc = __builtin_amdgcn_mfma_f32_16x16x32_bf16(al, wh, acc, 0, 0, 0);
  acc = __builtin_amdgcn_mfma_f32_16x16x32_bf16(ah, wl, acc, 0, 0, 0);
  return acc;
}

// ---------------- weight prep (W_ent only): split-bf16 frag table ----------------
// Frag fid = kt*4+n: lane l holds W[kt*32 + (l>>4)*8 + j][n*16 + (l&15)], j=0..7.
__global__ __launch_bounds__(256) void k_wprep(
    const float* __restrict__ Went,
    unsigned short* __restrict__ Fhi, unsigned short* __restrict__ Flo)
{
  const int gt = blockIdx.x * 256 + threadIdx.x;
  if (gt >= NFRAG * 64) return;
  const int fid = gt >> 6, lane = gt & 63;
  const int kt = fid >> 2, nn = fid & 3;
  const int col = nn * 16 + (lane & 15);
  const int r0  = kt * 32 + (lane >> 4) * 8;
  unsigned short* ph = Fhi + ((size_t)fid << 9) + lane * 8;
  unsigned short* pl = Flo + ((size_t)fid << 9) + lane * 8;
#pragma unroll
  for (int j = 0; j < 8; ++j){
    const float v = Went[(size_t)(r0 + j) * 64 + col];
    const unsigned short h = f2bf(v);
    ph[j] = h;
    pl[j] = f2bf(v - bf2f(h));
  }
}

// ---------------- entity encoder (MFMA): H0=H=LN(leaky(X@Went+b)) ----------------
// 64 rows/block; K=768 in 6 chunks of 128, staged split-bf16 in LDS (XOR swizzle).
__global__ __launch_bounds__(256) void k_encm(const float* __restrict__ X,
    const unsigned short* __restrict__ Fhi, const unsigned short* __restrict__ Flo,
    const float* __restrict__ b, const float* __restrict__ g_,
    const float* __restrict__ be, float* __restrict__ o0, float* __restrict__ o1, int nrows)
{
  __shared__ unsigned short Ahi[64 * 128];
  __shared__ unsigned short Alo[64 * 128];
  const int tile = blockIdx.x * 64;
  const int tid = threadIdx.x;
  const int w = tid >> 6, lane = tid & 63, g = lane >> 4, lr = lane & 15;
  const int rowb = w * 16;

  f32x4 acc[4];
#pragma unroll
  for (int n = 0; n < 4; ++n){
    const float bv = b[n * 16 + lr];
    acc[n] = (f32x4){bv, bv, bv, bv};
  }

  for (int ch = 0; ch < 6; ++ch){
    __syncthreads();   // protect LDS from previous chunk's readers
    // stage 64 rows x 32 float4-chunks (= 128 cols) : 2048 tasks = 8 x 256
#pragma unroll
    for (int i = 0; i < 8; ++i){
      const int idx = tid + 256 * i;
      const int row = idx >> 5, c = idx & 31;
      int gr = tile + row; if (gr >= nrows) gr = nrows - 1;
      const float4 a = *(const float4*)&X[(size_t)gr * IN_DIM + ch * 128 + c * 4];
      ushort4 hi, lo; split4(a, hi, lo);
      const int ad = (row * 256 + c * 8) ^ ((row & 7) << 4);
      *(ushort4*)((char*)Ahi + ad) = hi;
      *(ushort4*)((char*)Alo + ad) = lo;
    }
    __syncthreads();

    bf16x8 Ah[4], Al[4];
#pragma unroll
    for (int kt = 0; kt < 4; ++kt){
      const int row = rowb + lr;
      const int ad = (row * 256 + kt * 64 + g * 16) ^ ((row & 7) << 4);
      Ah[kt] = *(const bf16x8*)((const char*)Ahi + ad);
      Al[kt] = *(const bf16x8*)((const char*)Alo + ad);
    }
    const int fb = ch * 16;
#pragma unroll
    for (int n = 0; n < 4; ++n)
#pragma unroll
      for (int kt = 0; kt < 4; ++kt){
        const size_t fo = (((size_t)(fb + kt * 4 + n)) << 9) + lane * 8;
        acc[n] = mfma3(Ah[kt], Al[kt], *(const bf16x8*)(Fhi + fo), *(const bf16x8*)(Flo + fo), acc[n]);
      }
  }

  // epilogue: leaky + LN over 64 cols (proven R4 k_eu pattern)
#pragma unroll
  for (int reg = 0; reg < 4; ++reg){
    const int lrow = rowb + g * 4 + reg;
    float v[4];
#pragma unroll
    for (int n = 0; n < 4; ++n) v[n] = leaky_(acc[n][reg]);
    float s = v[0] + v[1] + v[2] + v[3];
#pragma unroll
    for (int msk = 1; msk < 16; msk <<= 1) s += __shfl_xor(s, msk, 64);
    const float mu = s * 0.015625f;
    float q = 0.f;
#pragma unroll
    for (int n = 0; n < 4; ++n){ v[n] -= mu; q += v[n] * v[n]; }
#pragma unroll
    for (int msk = 1; msk < 16; msk <<= 1) q += __shfl_xor(q, msk, 64);
    const float rs = rsqrtf(q * 0.015625f + 1e-5f);
    const int r = tile + lrow;
    if (r < nrows){
#pragma unroll
      for (int n = 0; n < 4; ++n){
        const int col = n * 16 + lr;
        const float o = v[n] * rs * g_[col] + be[col];
        o0[(size_t)r * 64 + col] = o;
        o1[(size_t)r * 64 + col] = o;
      }
    }
  }
}

// ---------------- f32 encoder (rel table, 500 rows) ----------------
__global__ __launch_bounds__(256) void k_enc(const float* __restrict__ X,
    const float* __restrict__ W, const float* __restrict__ b,
    const float* __restrict__ g, const float* __restrict__ be,
    float* __restrict__ o0, float* __restrict__ o1, int nrows)
{
  const int w = threadIdx.x >> 6, d = threadIdx.x & 63;
  const int rbase = blockIdx.x * 16 + w * 4;
  int rows[4];
#pragma unroll
  for (int j = 0; j < 4; ++j){ int r = rbase + j; rows[j] = r < nrows ? r : nrows - 1; }
  float acc[4] = {0.f, 0.f, 0.f, 0.f};
  for (int k4 = 0; k4 < IN_DIM / 4; ++k4){
    const int k = k4 * 4;
    const float w0 = W[(k+0)*64+d], w1 = W[(k+1)*64+d];
    const float w2 = W[(k+2)*64+d], w3 = W[(k+3)*64+d];
#pragma unroll
    for (int j = 0; j < 4; ++j){
      const float4 a = *(const float4*)&X[(size_t)rows[j] * IN_DIM + k];
      acc[j] = fmaf(a.x, w0, fmaf(a.y, w1, fmaf(a.z, w2, fmaf(a.w, w3, acc[j]))));
    }
  }
#pragma unroll
  for (int j = 0; j < 4; ++j){
    const int r = rbase + j;
    if (r < nrows){
      float v = wln_(leaky_(acc[j] + b[d]), g[d], be[d]);
      o0[(size_t)r*64+d] = v;
      if (o1) o1[(size_t)r*64+d] = v;
    }
  }
}

// Generic small matmul: Y = X(nrows x 64) @ W(64 x 64) [+ bias]
__global__ __launch_bounds__(256) void k_xw(const float* __restrict__ X,
    const float* __restrict__ W, const float* __restrict__ bias,
    float* __restrict__ Y, int nrows)
{
  const int w = threadIdx.x >> 6, d = threadIdx.x & 63;
  const int rbase = blockIdx.x * 16 + w * 4;
  int rows[4];
#pragma unroll
  for (int j = 0; j < 4; ++j){ int r = rbase + j; rows[j] = r < nrows ? r : nrows - 1; }
  const float b0 = bias ? bias[d] : 0.f;
  float acc[4] = {b0, b0, b0, b0};
  for (int k4 = 0; k4 < 16; ++k4){
    const int k = k4 * 4;
    const float w0 = W[(k+0)*64+d], w1 = W[(k+1)*64+d];
    const float w2 = W[(k+2)*64+d], w3 = W[(k+3)*64+d];
#pragma unroll
    for (int j = 0; j < 4; ++j){
      const float4 a = *(const float4*)&X[(size_t)rows[j] * 64 + k];
      acc[j] = fmaf(a.x, w0, fmaf(a.y, w1, fmaf(a.z, w2, fmaf(a.w, w3, acc[j]))));
    }
  }
#pragma unroll
  for (int j = 0; j < 4; ++j){
    const int r = rbase + j;
    if (r < nrows) Y[(size_t)r*64+d] = acc[j];
  }
}

// Degree counts
__global__ __launch_bounds__(256) void k_cnt(const int* __restrict__ ht,
    int* __restrict__ cf, int* __restrict__ cb, int M)
{
  int m = blockIdx.x * 256 + threadIdx.x;
  if (m < M){
    atomicAdd(&cf[ht[2*m+1]], 1);
    atomicAdd(&cb[ht[2*m+0]], 1);
  }
}

__global__ __launch_bounds__(256) void k_scan(const int* __restrict__ cf,
    const int* __restrict__ cb, int* __restrict__ pos, int N)
{
  __shared__ int ws[4];
  const int tid = threadIdx.x, lane = tid & 63, w = tid >> 6;
  const int chunk = (N + 255) / 256;
  int s = 0;
  for (int i = 0; i < chunk; ++i){ int idx = tid * chunk + i; if (idx < N) s += cf[idx] + cb[idx]; }
  int v = s;
#pragma unroll
  for (int off = 1; off < 64; off <<= 1){ int t = __shfl_up(v, off, 64); if (lane >= off) v += t; }
  if (lane == 63) ws[w] = v;
  __syncthreads();
  int wbase = 0;
  for (int i = 0; i < w; ++i) wbase += ws[i];
  int run = wbase + v - s;
  for (int i = 0; i < chunk; ++i){
    int idx = tid * chunk + i;
    if (idx < N){ int t = cf[idx] + cb[idx]; pos[idx] = run; run += t; }
  }
}

__global__ __launch_bounds__(256) void k_slot(const int* __restrict__ ht,
    const int* __restrict__ rt, int* __restrict__ pos,
    int* __restrict__ srcf, int* __restrict__ er, int* __restrict__ rr, int M)
{
  const int j = blockIdx.x * 256 + threadIdx.x;
  if (j < 2 * M){
    const int fwd = (j < M) ? 1 : 0;
    const int e = fwd ? j : j - M;
    const int dst = fwd ? ht[2*e+1] : ht[2*e];
    const int src = fwd ? ht[2*e]   : ht[2*e+1];
    const int slot = atomicAdd(&pos[dst], 1);
    srcf[slot] = src | (fwd << 31);
    er[slot] = e;
    rr[slot] = rt[e];
  }
}

// CSR pull-sum
__global__ __launch_bounds__(256) void k_sum(const float* __restrict__ H,
    const float* __restrict__ E, const int* __restrict__ srcf,
    const int* __restrict__ eidx, const int* __restrict__ pos_end,
    const int* __restrict__ cf, const int* __restrict__ cb,
    float* __restrict__ Sall, int N)
{
  const int w = threadIdx.x >> 6, lane = threadIdx.x & 63;
  const int n = blockIdx.x * 4 + w;
  if (n >= N) return;
  const int end = pos_end[n];
  const int start = end - (cf[n] + cb[n]);
  float sf = 0.f, ef = 0.f, sb = 0.f, eb = 0.f;
#pragma unroll 4
  for (int i = start; i < end; ++i){
    const unsigned u = (unsigned)srcf[i];
    const int src = (int)(u & 0x7fffffffu);
    const int ev  = eidx[i];
    const float h = H[(size_t)src * 64 + lane];
    const float e = E[(size_t)ev  * 64 + lane];
    if (u >> 31){ sf += h; ef += e; }
    else        { sb += h; eb += e; }
  }
  float* S = Sall + (size_t)n * 256;
  S[       lane] = sf;
  S[ 64 + lane] = ef;
  S[128 + lane] = sb;
  S[192 + lane] = eb;
}

// Dense post-aggregation update
__global__ __launch_bounds__(256) void k_hupd2(float* __restrict__ H,
    const float* __restrict__ Sall, const int* __restrict__ cf, const int* __restrict__ cb,
    const float* __restrict__ Wf, const float* __restrict__ Wb,
    const float* __restrict__ bf, const float* __restrict__ bb,
    const float* __restrict__ g, const float* __restrict__ be, int N)
{
  const int w = threadIdx.x >> 6, d = threadIdx.x & 63;
  const int rbase = blockIdx.x * 16 + w * 4;
  int rows[4];
#pragma unroll
  for (int j = 0; j < 4; ++j){ int r = rbase + j; rows[j] = r < N ? r : N - 1; }
  float acc[4];
#pragma unroll
  for (int j = 0; j < 4; ++j)
    acc[j] = (float)cf[rows[j]] * bf[d] + (float)cb[rows[j]] * bb[d];
  for (int k4 = 0; k4 < 64; ++k4){
    const int k = k4 * 4;
    const float* Wsel = (k < 128) ? (Wf + k * 64) : (Wb + (k - 128) * 64);
    const float w0 = Wsel[0*64+d], w1 = Wsel[1*64+d];
    const float w2 = Wsel[2*64+d], w3 = Wsel[3*64+d];
#pragma unroll
    for (int j = 0; j < 4; ++j){
      const float4 a = *(const float4*)&Sall[(size_t)rows[j] * 256 + k];
      acc[j] = fmaf(a.x, w0, fmaf(a.y, w1, fmaf(a.z, w2, fmaf(a.w, w3, acc[j]))));
    }
  }
#pragma unroll
  for (int j = 0; j < 4; ++j){
    const int r = rbase + j;
    if (r < N){
      const float c = (float)(cf[r] + cb[r]);
      const float v = leaky_(acc[j] / c) + H[(size_t)r*64+d];
      H[(size_t)r*64+d] = wln_(v, g[d], be[d]);
    }
  }
}

// Layer-0 edge update, decomposed
__global__ __launch_bounds__(256) void k_eu2(const float* __restrict__ HW1,
    const float* __restrict__ HW3, const float* __restrict__ TE,
    const float* __restrict__ E0t, const int* __restrict__ ht,
    const int* __restrict__ rt, const float* __restrict__ g,
    const float* __restrict__ be, float* __restrict__ E1, int M)
{
  const int w = threadIdx.x >> 6, lane = threadIdx.x & 63;
  const int m = blockIdx.x * 4 + w;
  if (m >= M) return;
  const int h = ht[2*m], t = ht[2*m+1], r = rt[m];
  float v = HW1[(size_t)h*64+lane] + HW3[(size_t)t*64+lane] + TE[(size_t)r*64+lane];
  v = leaky_(v) + E0t[(size_t)r*64+lane];
  E1[(size_t)m*64+lane] = wln_(v, g[lane], be[lane]);
}

// ---- qi compaction ----
__global__ __launch_bounds__(256) void k_qcount(const int* __restrict__ q,
                                                int* __restrict__ bcnt, int M)
{
  const int j = blockIdx.x * 256 + threadIdx.x;
  const int have = (j < M) && (q[j] != 0);
  unsigned long long bal = __ballot(have);
  if ((threadIdx.x & 63) == 0) atomicAdd(&bcnt[blockIdx.x], (int)__popcll(bal));
}

__global__ __launch_bounds__(256) void k_qscan(int* __restrict__ bcnt, int nb)
{
  __shared__ int ws[4];
  const int tid = threadIdx.x, lane = tid & 63, w = tid >> 6;
  const int chunk = (nb + 255) / 256;
  int s = 0;
  for (int i = 0; i < chunk; ++i){ int idx = tid * chunk + i; if (idx < nb) s += bcnt[idx]; }
  int v = s;
#pragma unroll
  for (int off = 1; off < 64; off <<= 1){ int t = __shfl_up(v, off, 64); if (lane >= off) v += t; }
  if (lane == 63) ws[w] = v;
  __syncthreads();
  int wbase = 0;
  for (int i = 0; i < w; ++i) wbase += ws[i];
  int run = wbase + v - s;
  for (int i = 0; i < chunk; ++i){
    int idx = tid * chunk + i;
    if (idx < nb){ int t = bcnt[idx]; bcnt[idx] = run; run += t; }
  }
}

__global__ __launch_bounds__(256) void k_qemit(const int* __restrict__ q,
    const int* __restrict__ bcnt, int* __restrict__ qi, int M, int NQ)
{
  __shared__ int wb[4];
  const int j = blockIdx.x * 256 + threadIdx.x;
  const int lane = threadIdx.x & 63, w = threadIdx.x >> 6;
  const int have = (j < M) && (q[j] != 0);
  unsigned long long bal = __ballot(have);
  if (lane == 0) wb[w] = (int)__popcll(bal);
  __syncthreads();
  int base = bcnt[blockIdx.x];
  for (int i = 0; i < w; ++i) base += wb[i];
  const int rank = base + (int)__popcll(bal & ((1ull << lane) - 1ull));
  if (have && rank < NQ) qi[rank] = j;
}

// Layer-1 edge update for query rows only + feature assembly.
__global__ __launch_bounds__(256) void k_feat(
    const float* __restrict__ H, const float* __restrict__ H0,
    const float* __restrict__ E1, const float* __restrict__ E0t,
    const int* __restrict__ rt, const int* __restrict__ ht, const int* __restrict__ qi,
    const float* __restrict__ W, const float* __restrict__ b,
    const float* __restrict__ g, const float* __restrict__ be,
    float* __restrict__ feat, int NQ)
{
  const int w = threadIdx.x >> 6, d = threadIdx.x & 63;
  const int row = blockIdx.x * 4 + w;
  if (row >= NQ) return;
  const int m = qi[row];
  const int h = ht[2*m], t = ht[2*m+1], r = rt[m];
  const float* seg0 = H  + (size_t)h * 64;
  const float* seg1 = E1 + (size_t)m * 64;
  const float* seg2 = H  + (size_t)t * 64;
  float acc = b[d];
  for (int k4 = 0; k4 < 48; ++k4){
    const int k = k4 * 4;
    const float* A = (k4 < 16) ? seg0 : (k4 < 32) ? seg1 - 64 : seg2 - 128;
    const float4 a = *(const float4*)&A[k];
    acc = fmaf(a.x, W[(k+0)*64+d], fmaf(a.y, W[(k+1)*64+d],
          fmaf(a.z, W[(k+2)*64+d], fmaf(a.w, W[(k+3)*64+d], acc))));
  }
  const float ep = E1[(size_t)m*64+d];
  const float e2 = wln_(leaky_(acc) + ep, g[d], be[d]);
  float* F = feat + (size_t)row * 384;
  F[      d] = e2;
  F[ 64 + d] = E0t[(size_t)r*64+d];
  F[128 + d] = H [(size_t)h*64+d];
  F[192 + d] = H0[(size_t)h*64+d];
  F[256 + d] = H [(size_t)t*64+d];
  F[320 + d] = H0[(size_t)t*64+d];
}

__global__ __launch_bounds__(256) void k_cls(const float* __restrict__ feat,
    const float* __restrict__ W1, const float* __restrict__ b1,
    const float* __restrict__ W2, const float* __restrict__ b2,
    float* __restrict__ out, int NQ)
{
  const int w = threadIdx.x >> 6, d = threadIdx.x & 63;
  const int row = blockIdx.x * 4 + w;
  if (row >= NQ) return;
  const float* F = feat + (size_t)row * 384;
  float acc = b1[d];
  for (int k4 = 0; k4 < 96; ++k4){
    const int k = k4 * 4;
    const float4 a = *(const float4*)&F[k];
    acc = fmaf(a.x, W1[(k+0)*64+d], fmaf(a.y, W1[(k+1)*64+d],
          fmaf(a.z, W1[(k+2)*64+d], fmaf(a.w, W1[(k+3)*64+d], acc))));
  }
  float hs = leaky_(acc) * W2[d];
  hs = wsum_(hs);
  if (d == 0) out[row] = hs + b2[0];
}

extern "C" void kernel_launch(void* const* d_in, const int* in_sizes, int n_in,
                              void* d_out, int out_size, void* d_ws, size_t ws_size,
                              hipStream_t stream)
{
  const int*   ht    = (const int*)  d_in[0];
  const int*   rt    = (const int*)  d_in[1];
  const float* ef    = (const float*)d_in[2];
  const int*   q     = (const int*)  d_in[3];
  const float* rtab  = (const float*)d_in[4];
  const float* W_ent = (const float*)d_in[5];
  const float* b_ent = (const float*)d_in[6];
  const float* g_ent = (const float*)d_in[7];
  const float* be_ent= (const float*)d_in[8];
  const float* W_ein = (const float*)d_in[9];
  const float* b_ein = (const float*)d_in[10];
  const float* g_e   = (const float*)d_in[11];
  const float* be_e  = (const float*)d_in[12];
  const float* mp_Wf = (const float*)d_in[13];
  const float* mp_bf = (const float*)d_in[14];
  const float* mp_Wb = (const float*)d_in[15];
  const float* mp_bb = (const float*)d_in[16];
  const float* mp_g  = (const float*)d_in[17];
  const float* mp_be = (const float*)d_in[18];
  const float* eu_W  = (const float*)d_in[19];
  const float* eu_b  = (const float*)d_in[20];
  const float* eu_g  = (const float*)d_in[21];
  const float* eu_be = (const float*)d_in[22];
  const float* clsW1 = (const float*)d_in[23];
  const float* clsb1 = (const float*)d_in[24];
  const float* clsW2 = (const float*)d_in[25];
  const float* clsb2 = (const float*)d_in[26];

  const int M    = in_sizes[1];
  const int N    = in_sizes[2] / IN_DIM;
  const int NREL = in_sizes[4] / IN_DIM;
  const int NQ   = out_size;
  const int nb   = (M + 255) / 256;

  unsigned short* Fhi = (unsigned short*)d_ws;           // NFRAG*512 ushorts
  unsigned short* Flo = Fhi + (size_t)NFRAG * 512;
  float* H0   = (float*)(Flo + (size_t)NFRAG * 512);
  float* H    = H0   + (size_t)N * 64;
  float* HW1  = H    + (size_t)N * 64;
  float* HW3  = HW1  + (size_t)N * 64;
  float* Sall = HW3  + (size_t)N * 64;
  float* E1   = Sall + (size_t)N * 256;
  float* E0t  = E1   + (size_t)M * 64;
  float* TE   = E0t  + (size_t)NREL * 64;
  float* feat = TE   + (size_t)NREL * 64;
  int*   cf   = (int*)(feat + (size_t)NQ * 384);
  int*   cb   = cf + N;
  int*   pos  = cb + N;
  int*   srcf = pos + N;
  int*   er   = srcf + 2 * (size_t)M;
  int*   rr   = er   + 2 * (size_t)M;
  int*   qi   = rr   + 2 * (size_t)M;
  int*   bcnt = qi + NQ;

  hipMemsetAsync(cf,   0, (size_t)N  * 4, stream);
  hipMemsetAsync(cb,   0, (size_t)N  * 4, stream);
  hipMemsetAsync(qi,   0, (size_t)NQ * 4, stream);
  hipMemsetAsync(bcnt, 0, (size_t)nb * 4, stream);

  // CSR build + frag table
  k_wprep<<<(NFRAG * 64 + 255) / 256, 256, 0, stream>>>(W_ent, Fhi, Flo);
  k_cnt<<<(M + 255) / 256, 256, 0, stream>>>(ht, cf, cb, M);
  k_scan<<<1, 256, 0, stream>>>(cf, cb, pos, N);
  k_slot<<<(2 * M + 255) / 256, 256, 0, stream>>>(ht, rt, pos, srcf, er, rr, M);

  // Encoders + eu layer-0 E-table
  k_encm<<<(N + 63) / 64, 256, 0, stream>>>(ef, Fhi, Flo, b_ent, g_ent, be_ent, H0, H, N);
  k_enc<<<(NREL + 15) / 16, 256, 0, stream>>>(rtab, W_ein, b_ein, g_e, be_e, E0t, nullptr, NREL);
  k_xw<<<(NREL + 15) / 16, 256, 0, stream>>>(E0t, eu_W + 64 * 64, eu_b, TE, NREL);

  // ---- layer 0 ----
  k_sum<<<(N + 3) / 4, 256, 0, stream>>>(H, E0t, srcf, rr, pos, cf, cb, Sall, N);
  k_hupd2<<<(N + 15) / 16, 256, 0, stream>>>(H, Sall, cf, cb,
      mp_Wf, mp_Wb, mp_bf, mp_bb, mp_g, mp_be, N);
  k_xw<<<(N + 15) / 16, 256, 0, stream>>>(H, eu_W, nullptr, HW1, N);
  k_xw<<<(N + 15) / 16, 256, 0, stream>>>(H, eu_W + 128 * 64, nullptr, HW3, N);
  k_eu2<<<(M + 3) / 4, 256, 0, stream>>>(HW1, HW3, TE, E0t, ht, rt, eu_g, eu_be, E1, M);

  // ---- layer 1 ----
  k_sum<<<(N + 3) / 4, 256, 0, stream>>>(H, E1, srcf, er, pos, cf, cb, Sall, N);
  k_hupd2<<<(N + 15) / 16, 256, 0, stream>>>(H, Sall, cf, cb,
      mp_Wf + 128 * 64, mp_Wb + 128 * 64, mp_bf + 64, mp_bb + 64,
      mp_g + 64, mp_be + 64, N);

  // qi compaction
  k_qcount<<<nb, 256, 0, stream>>>(q, bcnt, M);
  k_qscan<<<1, 256, 0, stream>>>(bcnt, nb);
  k_qemit<<<nb, 256, 0, stream>>>(q, bcnt, qi, M, NQ);

  // features + classifier
  k_feat<<<(NQ + 3) / 4, 256, 0, stream>>>(H, H0, E1, E0t, rt, ht, qi,
      eu_W + 192 * 64, eu_b + 64, eu_g + 64, eu_be + 64, feat, NQ);
  k_cls<<<(NQ + 3) / 4, 256, 0, stream>>>(feat, clsW1, clsb1, clsW2, clsb2,
      (float*)d_out, NQ);
}

// Round 8
// 1157.063 us; speedup vs baseline: 1.9959x; 1.0236x over previous
//
#include <hip/hip_runtime.h>
#include <hip/hip_bf16.h>
#include <cstdint>

constexpr int IN_DIM = 768;
constexpr int NFRAG  = 96;   // W_ent (768x64) -> 24 kt x 4 n

typedef __attribute__((ext_vector_type(8))) short bf16x8;
typedef __attribute__((ext_vector_type(4))) float f32x4;

static __device__ __forceinline__ float leaky_(float x){ return x >= 0.0f ? x : 0.01f * x; }

static __device__ __forceinline__ float wsum_(float v){
#pragma unroll
  for (int m = 1; m < 64; m <<= 1) v += __shfl_xor(v, m, 64);
  return v;
}

static __device__ __forceinline__ float wln_(float v, float g, float be){
  float mu  = wsum_(v) * 0.015625f;
  float c   = v - mu;
  float var = wsum_(c * c) * 0.015625f;
  return c * rsqrtf(var + 1e-5f) * g + be;
}

static __device__ __forceinline__ unsigned short f2bf(float x){
  return __bfloat16_as_ushort(__float2bfloat16(x));
}
static __device__ __forceinline__ float bf2f(unsigned short u){
  return __bfloat162float(__ushort_as_bfloat16(u));
}
static __device__ __forceinline__ void split4(const float4 a, ushort4& hi, ushort4& lo){
  hi.x = f2bf(a.x); lo.x = f2bf(a.x - bf2f(hi.x));
  hi.y = f2bf(a.y); lo.y = f2bf(a.y - bf2f(hi.y));
  hi.z = f2bf(a.z); lo.z = f2bf(a.z - bf2f(hi.z));
  hi.w = f2bf(a.w); lo.w = f2bf(a.w - bf2f(hi.w));
}

static __device__ __forceinline__ f32x4 mfma3(bf16x8 ah, bf16x8 al, bf16x8 wh, bf16x8 wl, f32x4 acc){
  acc = __builtin_amdgcn_mfma_f32_16x16x32_bf16(ah, wh, acc, 0, 0, 0);
  acc = __builtin_amdgcn_mfma_f32_16x16x32_bf16(al, wh, acc, 0, 0, 0);
  acc = __builtin_amdgcn_mfma_f32_16x16x32_bf16(ah, wl, acc, 0, 0, 0);
  return acc;
}

// ---------------- weight prep (W_ent only): split-bf16 frag table ----------------
__global__ __launch_bounds__(256) void k_wprep(
    const float* __restrict__ Went,
    unsigned short* __restrict__ Fhi, unsigned short* __restrict__ Flo)
{
  const int gt = blockIdx.x * 256 + threadIdx.x;
  if (gt >= NFRAG * 64) return;
  const int fid = gt >> 6, lane = gt & 63;
  const int kt = fid >> 2, nn = fid & 3;
  const int col = nn * 16 + (lane & 15);
  const int r0  = kt * 32 + (lane >> 4) * 8;
  unsigned short* ph = Fhi + ((size_t)fid << 9) + lane * 8;
  unsigned short* pl = Flo + ((size_t)fid << 9) + lane * 8;
#pragma unroll
  for (int j = 0; j < 8; ++j){
    const float v = Went[(size_t)(r0 + j) * 64 + col];
    const unsigned short h = f2bf(v);
    ph[j] = h;
    pl[j] = f2bf(v - bf2f(h));
  }
}

// ---------------- entity encoder (MFMA): H0=H=LN(leaky(X@Went+b)) ----------------
__global__ __launch_bounds__(256) void k_encm(const float* __restrict__ X,
    const unsigned short* __restrict__ Fhi, const unsigned short* __restrict__ Flo,
    const float* __restrict__ b, const float* __restrict__ g_,
    const float* __restrict__ be, float* __restrict__ o0, float* __restrict__ o1, int nrows)
{
  __shared__ unsigned short Ahi[64 * 128];
  __shared__ unsigned short Alo[64 * 128];
  const int tile = blockIdx.x * 64;
  const int tid = threadIdx.x;
  const int w = tid >> 6, lane = tid & 63, g = lane >> 4, lr = lane & 15;
  const int rowb = w * 16;

  f32x4 acc[4];
#pragma unroll
  for (int n = 0; n < 4; ++n){
    const float bv = b[n * 16 + lr];
    acc[n] = (f32x4){bv, bv, bv, bv};
  }

  for (int ch = 0; ch < 6; ++ch){
    __syncthreads();
#pragma unroll
    for (int i = 0; i < 8; ++i){
      const int idx = tid + 256 * i;
      const int row = idx >> 5, c = idx & 31;
      int gr = tile + row; if (gr >= nrows) gr = nrows - 1;
      const float4 a = *(const float4*)&X[(size_t)gr * IN_DIM + ch * 128 + c * 4];
      ushort4 hi, lo; split4(a, hi, lo);
      const int ad = (row * 256 + c * 8) ^ ((row & 7) << 4);
      *(ushort4*)((char*)Ahi + ad) = hi;
      *(ushort4*)((char*)Alo + ad) = lo;
    }
    __syncthreads();

    bf16x8 Ah[4], Al[4];
#pragma unroll
    for (int kt = 0; kt < 4; ++kt){
      const int row = rowb + lr;
      const int ad = (row * 256 + kt * 64 + g * 16) ^ ((row & 7) << 4);
      Ah[kt] = *(const bf16x8*)((const char*)Ahi + ad);
      Al[kt] = *(const bf16x8*)((const char*)Alo + ad);
    }
    const int fb = ch * 16;
#pragma unroll
    for (int n = 0; n < 4; ++n)
#pragma unroll
      for (int kt = 0; kt < 4; ++kt){
        const size_t fo = (((size_t)(fb + kt * 4 + n)) << 9) + lane * 8;
        acc[n] = mfma3(Ah[kt], Al[kt], *(const bf16x8*)(Fhi + fo), *(const bf16x8*)(Flo + fo), acc[n]);
      }
  }

#pragma unroll
  for (int reg = 0; reg < 4; ++reg){
    const int lrow = rowb + g * 4 + reg;
    float v[4];
#pragma unroll
    for (int n = 0; n < 4; ++n) v[n] = leaky_(acc[n][reg]);
    float s = v[0] + v[1] + v[2] + v[3];
#pragma unroll
    for (int msk = 1; msk < 16; msk <<= 1) s += __shfl_xor(s, msk, 64);
    const float mu = s * 0.015625f;
    float q = 0.f;
#pragma unroll
    for (int n = 0; n < 4; ++n){ v[n] -= mu; q += v[n] * v[n]; }
#pragma unroll
    for (int msk = 1; msk < 16; msk <<= 1) q += __shfl_xor(q, msk, 64);
    const float rs = rsqrtf(q * 0.015625f + 1e-5f);
    const int r = tile + lrow;
    if (r < nrows){
#pragma unroll
      for (int n = 0; n < 4; ++n){
        const int col = n * 16 + lr;
        const float o = v[n] * rs * g_[col] + be[col];
        o0[(size_t)r * 64 + col] = o;
        o1[(size_t)r * 64 + col] = o;
      }
    }
  }
}

// ---------------- f32 encoder (rel table, 500 rows) ----------------
__global__ __launch_bounds__(256) void k_enc(const float* __restrict__ X,
    const float* __restrict__ W, const float* __restrict__ b,
    const float* __restrict__ g, const float* __restrict__ be,
    float* __restrict__ o0, float* __restrict__ o1, int nrows)
{
  const int w = threadIdx.x >> 6, d = threadIdx.x & 63;
  const int rbase = blockIdx.x * 16 + w * 4;
  int rows[4];
#pragma unroll
  for (int j = 0; j < 4; ++j){ int r = rbase + j; rows[j] = r < nrows ? r : nrows - 1; }
  float acc[4] = {0.f, 0.f, 0.f, 0.f};
  for (int k4 = 0; k4 < IN_DIM / 4; ++k4){
    const int k = k4 * 4;
    const float w0 = W[(k+0)*64+d], w1 = W[(k+1)*64+d];
    const float w2 = W[(k+2)*64+d], w3 = W[(k+3)*64+d];
#pragma unroll
    for (int j = 0; j < 4; ++j){
      const float4 a = *(const float4*)&X[(size_t)rows[j] * IN_DIM + k];
      acc[j] = fmaf(a.x, w0, fmaf(a.y, w1, fmaf(a.z, w2, fmaf(a.w, w3, acc[j]))));
    }
  }
#pragma unroll
  for (int j = 0; j < 4; ++j){
    const int r = rbase + j;
    if (r < nrows){
      float v = wln_(leaky_(acc[j] + b[d]), g[d], be[d]);
      o0[(size_t)r*64+d] = v;
      if (o1) o1[(size_t)r*64+d] = v;
    }
  }
}

// Generic small matmul: Y = X(nrows x 64) @ W(64 x 64) [+ bias]
__global__ __launch_bounds__(256) void k_xw(const float* __restrict__ X,
    const float* __restrict__ W, const float* __restrict__ bias,
    float* __restrict__ Y, int nrows)
{
  const int w = threadIdx.x >> 6, d = threadIdx.x & 63;
  const int rbase = blockIdx.x * 16 + w * 4;
  int rows[4];
#pragma unroll
  for (int j = 0; j < 4; ++j){ int r = rbase + j; rows[j] = r < nrows ? r : nrows - 1; }
  const float b0 = bias ? bias[d] : 0.f;
  float acc[4] = {b0, b0, b0, b0};
  for (int k4 = 0; k4 < 16; ++k4){
    const int k = k4 * 4;
    const float w0 = W[(k+0)*64+d], w1 = W[(k+1)*64+d];
    const float w2 = W[(k+2)*64+d], w3 = W[(k+3)*64+d];
#pragma unroll
    for (int j = 0; j < 4; ++j){
      const float4 a = *(const float4*)&X[(size_t)rows[j] * 64 + k];
      acc[j] = fmaf(a.x, w0, fmaf(a.y, w1, fmaf(a.z, w2, fmaf(a.w, w3, acc[j]))));
    }
  }
#pragma unroll
  for (int j = 0; j < 4; ++j){
    const int r = rbase + j;
    if (r < nrows) Y[(size_t)r*64+d] = acc[j];
  }
}

// Degree counts
__global__ __launch_bounds__(256) void k_cnt(const int* __restrict__ ht,
    int* __restrict__ cf, int* __restrict__ cb, int M)
{
  int m = blockIdx.x * 256 + threadIdx.x;
  if (m < M){
    atomicAdd(&cf[ht[2*m+1]], 1);
    atomicAdd(&cb[ht[2*m+0]], 1);
  }
}

__global__ __launch_bounds__(256) void k_scan(const int* __restrict__ cf,
    const int* __restrict__ cb, int* __restrict__ pos, int N)
{
  __shared__ int ws[4];
  const int tid = threadIdx.x, lane = tid & 63, w = tid >> 6;
  const int chunk = (N + 255) / 256;
  int s = 0;
  for (int i = 0; i < chunk; ++i){ int idx = tid * chunk + i; if (idx < N) s += cf[idx] + cb[idx]; }
  int v = s;
#pragma unroll
  for (int off = 1; off < 64; off <<= 1){ int t = __shfl_up(v, off, 64); if (lane >= off) v += t; }
  if (lane == 63) ws[w] = v;
  __syncthreads();
  int wbase = 0;
  for (int i = 0; i < w; ++i) wbase += ws[i];
  int run = wbase + v - s;
  for (int i = 0; i < chunk; ++i){
    int idx = tid * chunk + i;
    if (idx < N){ int t = cf[idx] + cb[idx]; pos[idx] = run; run += t; }
  }
}

// Counting-sort scatter. srcf[slot] = src | (fwd<<31); rr[slot] = rt[edge].
__global__ __launch_bounds__(256) void k_slot(const int* __restrict__ ht,
    const int* __restrict__ rt, int* __restrict__ pos,
    int* __restrict__ srcf, int* __restrict__ rr, int M)
{
  const int j = blockIdx.x * 256 + threadIdx.x;
  if (j < 2 * M){
    const int fwd = (j < M) ? 1 : 0;
    const int e = fwd ? j : j - M;
    const int dst = fwd ? ht[2*e+1] : ht[2*e];
    const int src = fwd ? ht[2*e]   : ht[2*e+1];
    const int slot = atomicAdd(&pos[dst], 1);
    srcf[slot] = src | (fwd << 31);
    rr[slot] = rt[e];
  }
}

// Layer-0 CSR pull-sum (E gathered from E0t by relation)
__global__ __launch_bounds__(256) void k_sum(const float* __restrict__ H,
    const float* __restrict__ E, const int* __restrict__ srcf,
    const int* __restrict__ eidx, const int* __restrict__ pos_end,
    const int* __restrict__ cf, const int* __restrict__ cb,
    float* __restrict__ Sall, int N)
{
  const int w = threadIdx.x >> 6, lane = threadIdx.x & 63;
  const int n = blockIdx.x * 4 + w;
  if (n >= N) return;
  const int end = pos_end[n];
  const int start = end - (cf[n] + cb[n]);
  float sf = 0.f, ef = 0.f, sb = 0.f, eb = 0.f;
#pragma unroll 4
  for (int i = start; i < end; ++i){
    const unsigned u = (unsigned)srcf[i];
    const int src = (int)(u & 0x7fffffffu);
    const int ev  = eidx[i];
    const float h = H[(size_t)src * 64 + lane];
    const float e = E[(size_t)ev  * 64 + lane];
    if (u >> 31){ sf += h; ef += e; }
    else        { sb += h; eb += e; }
  }
  float* S = Sall + (size_t)n * 256;
  S[       lane] = sf;
  S[ 64 + lane] = ef;
  S[128 + lane] = sb;
  S[192 + lane] = eb;
}

// Layer-1 CSR pull-sum with FUSED on-the-fly edge update (no E1 buffer).
// For slot at node n: fwd -> h=src,t=n ; bwd -> h=n,t=src.
// e1 = LN(leaky(HW1[h]+HW3[t]+TE[r]) + E0t[r]).
__global__ __launch_bounds__(256) void k_sum2(const float* __restrict__ H,
    const float* __restrict__ HW1, const float* __restrict__ HW3,
    const float* __restrict__ TE, const float* __restrict__ E0t,
    const int* __restrict__ srcf, const int* __restrict__ rr,
    const int* __restrict__ pos_end, const int* __restrict__ cf,
    const int* __restrict__ cb,
    const float* __restrict__ g0, const float* __restrict__ be0,
    float* __restrict__ Sall, int N)
{
  const int w = threadIdx.x >> 6, lane = threadIdx.x & 63;
  const int n = blockIdx.x * 4 + w;
  if (n >= N) return;
  const int end = pos_end[n];
  const int start = end - (cf[n] + cb[n]);
  const float gg = g0[lane], bb = be0[lane];
  const float hw1n = HW1[(size_t)n * 64 + lane];   // t=n term for fwd? no: h=n for bwd
  const float hw3n = HW3[(size_t)n * 64 + lane];   // t=n term for fwd
  float sf = 0.f, ef = 0.f, sb = 0.f, eb = 0.f;
  for (int i = start; i < end; ++i){
    const unsigned u = (unsigned)srcf[i];
    const int src = (int)(u & 0x7fffffffu);
    const int r = rr[i];
    const bool fwd = (u >> 31) != 0;                // wave-uniform
    const float hv = H[(size_t)src * 64 + lane];
    const float other = fwd ? HW1[(size_t)src * 64 + lane]   // h=src
                            : HW3[(size_t)src * 64 + lane];  // t=src
    float v = (fwd ? other + hw3n : hw1n + other) + TE[(size_t)r * 64 + lane];
    v = leaky_(v) + E0t[(size_t)r * 64 + lane];
    const float e1 = wln_(v, gg, bb);
    if (fwd){ sf += hv; ef += e1; }
    else    { sb += hv; eb += e1; }
  }
  float* S = Sall + (size_t)n * 256;
  S[       lane] = sf;
  S[ 64 + lane] = ef;
  S[128 + lane] = sb;
  S[192 + lane] = eb;
}

// Dense post-aggregation update
__global__ __launch_bounds__(256) void k_hupd2(float* __restrict__ H,
    const float* __restrict__ Sall, const int* __restrict__ cf, const int* __restrict__ cb,
    const float* __restrict__ Wf, const float* __restrict__ Wb,
    const float* __restrict__ bf, const float* __restrict__ bb,
    const float* __restrict__ g, const float* __restrict__ be, int N)
{
  const int w = threadIdx.x >> 6, d = threadIdx.x & 63;
  const int rbase = blockIdx.x * 16 + w * 4;
  int rows[4];
#pragma unroll
  for (int j = 0; j < 4; ++j){ int r = rbase + j; rows[j] = r < N ? r : N - 1; }
  float acc[4];
#pragma unroll
  for (int j = 0; j < 4; ++j)
    acc[j] = (float)cf[rows[j]] * bf[d] + (float)cb[rows[j]] * bb[d];
  for (int k4 = 0; k4 < 64; ++k4){
    const int k = k4 * 4;
    const float* Wsel = (k < 128) ? (Wf + k * 64) : (Wb + (k - 128) * 64);
    const float w0 = Wsel[0*64+d], w1 = Wsel[1*64+d];
    const float w2 = Wsel[2*64+d], w3 = Wsel[3*64+d];
#pragma unroll
    for (int j = 0; j < 4; ++j){
      const float4 a = *(const float4*)&Sall[(size_t)rows[j] * 256 + k];
      acc[j] = fmaf(a.x, w0, fmaf(a.y, w1, fmaf(a.z, w2, fmaf(a.w, w3, acc[j]))));
    }
  }
#pragma unroll
  for (int j = 0; j < 4; ++j){
    const int r = rbase + j;
    if (r < N){
      const float c = (float)(cf[r] + cb[r]);
      const float v = leaky_(acc[j] / c) + H[(size_t)r*64+d];
      H[(size_t)r*64+d] = wln_(v, g[d], be[d]);
    }
  }
}

// Query-rows-only layer-0 edge update: e1q[row] = E1[qi[row]]
__global__ __launch_bounds__(256) void k_eu2q(const float* __restrict__ HW1,
    const float* __restrict__ HW3, const float* __restrict__ TE,
    const float* __restrict__ E0t, const int* __restrict__ ht,
    const int* __restrict__ rt, const int* __restrict__ qi,
    const float* __restrict__ g, const float* __restrict__ be,
    float* __restrict__ e1q, int NQ)
{
  const int w = threadIdx.x >> 6, lane = threadIdx.x & 63;
  const int row = blockIdx.x * 4 + w;
  if (row >= NQ) return;
  const int m = qi[row];
  const int h = ht[2*m], t = ht[2*m+1], r = rt[m];
  float v = HW1[(size_t)h*64+lane] + HW3[(size_t)t*64+lane] + TE[(size_t)r*64+lane];
  v = leaky_(v) + E0t[(size_t)r*64+lane];
  e1q[(size_t)row*64+lane] = wln_(v, g[lane], be[lane]);
}

// ---- qi compaction ----
__global__ __launch_bounds__(256) void k_qcount(const int* __restrict__ q,
                                                int* __restrict__ bcnt, int M)
{
  const int j = blockIdx.x * 256 + threadIdx.x;
  const int have = (j < M) && (q[j] != 0);
  unsigned long long bal = __ballot(have);
  if ((threadIdx.x & 63) == 0) atomicAdd(&bcnt[blockIdx.x], (int)__popcll(bal));
}

__global__ __launch_bounds__(256) void k_qscan(int* __restrict__ bcnt, int nb)
{
  __shared__ int ws[4];
  const int tid = threadIdx.x, lane = tid & 63, w = tid >> 6;
  const int chunk = (nb + 255) / 256;
  int s = 0;
  for (int i = 0; i < chunk; ++i){ int idx = tid * chunk + i; if (idx < nb) s += bcnt[idx]; }
  int v = s;
#pragma unroll
  for (int off = 1; off < 64; off <<= 1){ int t = __shfl_up(v, off, 64); if (lane >= off) v += t; }
  if (lane == 63) ws[w] = v;
  __syncthreads();
  int wbase = 0;
  for (int i = 0; i < w; ++i) wbase += ws[i];
  int run = wbase + v - s;
  for (int i = 0; i < chunk; ++i){
    int idx = tid * chunk + i;
    if (idx < nb){ int t = bcnt[idx]; bcnt[idx] = run; run += t; }
  }
}

__global__ __launch_bounds__(256) void k_qemit(const int* __restrict__ q,
    const int* __restrict__ bcnt, int* __restrict__ qi, int M, int NQ)
{
  __shared__ int wb[4];
  const int j = blockIdx.x * 256 + threadIdx.x;
  const int lane = threadIdx.x & 63, w = threadIdx.x >> 6;
  const int have = (j < M) && (q[j] != 0);
  unsigned long long bal = __ballot(have);
  if (lane == 0) wb[w] = (int)__popcll(bal);
  __syncthreads();
  int base = bcnt[blockIdx.x];
  for (int i = 0; i < w; ++i) base += wb[i];
  const int rank = base + (int)__popcll(bal & ((1ull << lane) - 1ull));
  if (have && rank < NQ) qi[rank] = j;
}

// Layer-1 edge update at query rows + feature assembly (E1 from e1q).
__global__ __launch_bounds__(256) void k_feat(
    const float* __restrict__ H, const float* __restrict__ H0,
    const float* __restrict__ e1q, const float* __restrict__ E0t,
    const int* __restrict__ rt, const int* __restrict__ ht, const int* __restrict__ qi,
    const float* __restrict__ W, const float* __restrict__ b,
    const float* __restrict__ g, const float* __restrict__ be,
    float* __restrict__ feat, int NQ)
{
  const int w = threadIdx.x >> 6, d = threadIdx.x & 63;
  const int row = blockIdx.x * 4 + w;
  if (row >= NQ) return;
  const int m = qi[row];
  const int h = ht[2*m], t = ht[2*m+1], r = rt[m];
  const float* seg0 = H   + (size_t)h * 64;
  const float* seg1 = e1q + (size_t)row * 64;
  const float* seg2 = H   + (size_t)t * 64;
  float acc = b[d];
  for (int k4 = 0; k4 < 48; ++k4){
    const int k = k4 * 4;
    const float* A = (k4 < 16) ? seg0 : (k4 < 32) ? seg1 - 64 : seg2 - 128;
    const float4 a = *(const float4*)&A[k];
    acc = fmaf(a.x, W[(k+0)*64+d], fmaf(a.y, W[(k+1)*64+d],
          fmaf(a.z, W[(k+2)*64+d], fmaf(a.w, W[(k+3)*64+d], acc))));
  }
  const float ep = seg1[d];
  const float e2 = wln_(leaky_(acc) + ep, g[d], be[d]);
  float* F = feat + (size_t)row * 384;
  F[      d] = e2;
  F[ 64 + d] = E0t[(size_t)r*64+d];
  F[128 + d] = H [(size_t)h*64+d];
  F[192 + d] = H0[(size_t)h*64+d];
  F[256 + d] = H [(size_t)t*64+d];
  F[320 + d] = H0[(size_t)t*64+d];
}

__global__ __launch_bounds__(256) void k_cls(const float* __restrict__ feat,
    const float* __restrict__ W1, const float* __restrict__ b1,
    const float* __restrict__ W2, const float* __restrict__ b2,
    float* __restrict__ out, int NQ)
{
  const int w = threadIdx.x >> 6, d = threadIdx.x & 63;
  const int row = blockIdx.x * 4 + w;
  if (row >= NQ) return;
  const float* F = feat + (size_t)row * 384;
  float acc = b1[d];
  for (int k4 = 0; k4 < 96; ++k4){
    const int k = k4 * 4;
    const float4 a = *(const float4*)&F[k];
    acc = fmaf(a.x, W1[(k+0)*64+d], fmaf(a.y, W1[(k+1)*64+d],
          fmaf(a.z, W1[(k+2)*64+d], fmaf(a.w, W1[(k+3)*64+d], acc))));
  }
  float hs = leaky_(acc) * W2[d];
  hs = wsum_(hs);
  if (d == 0) out[row] = hs + b2[0];
}

extern "C" void kernel_launch(void* const* d_in, const int* in_sizes, int n_in,
                              void* d_out, int out_size, void* d_ws, size_t ws_size,
                              hipStream_t stream)
{
  const int*   ht    = (const int*)  d_in[0];
  const int*   rt    = (const int*)  d_in[1];
  const float* ef    = (const float*)d_in[2];
  const int*   q     = (const int*)  d_in[3];
  const float* rtab  = (const float*)d_in[4];
  const float* W_ent = (const float*)d_in[5];
  const float* b_ent = (const float*)d_in[6];
  const float* g_ent = (const float*)d_in[7];
  const float* be_ent= (const float*)d_in[8];
  const float* W_ein = (const float*)d_in[9];
  const float* b_ein = (const float*)d_in[10];
  const float* g_e   = (const float*)d_in[11];
  const float* be_e  = (const float*)d_in[12];
  const float* mp_Wf = (const float*)d_in[13];
  const float* mp_bf = (const float*)d_in[14];
  const float* mp_Wb = (const float*)d_in[15];
  const float* mp_bb = (const float*)d_in[16];
  const float* mp_g  = (const float*)d_in[17];
  const float* mp_be = (const float*)d_in[18];
  const float* eu_W  = (const float*)d_in[19];
  const float* eu_b  = (const float*)d_in[20];
  const float* eu_g  = (const float*)d_in[21];
  const float* eu_be = (const float*)d_in[22];
  const float* clsW1 = (const float*)d_in[23];
  const float* clsb1 = (const float*)d_in[24];
  const float* clsW2 = (const float*)d_in[25];
  const float* clsb2 = (const float*)d_in[26];

  const int M    = in_sizes[1];
  const int N    = in_sizes[2] / IN_DIM;
  const int NREL = in_sizes[4] / IN_DIM;
  const int NQ   = out_size;
  const int nb   = (M + 255) / 256;

  unsigned short* Fhi = (unsigned short*)d_ws;           // NFRAG*512 ushorts
  unsigned short* Flo = Fhi + (size_t)NFRAG * 512;
  float* H0   = (float*)(Flo + (size_t)NFRAG * 512);
  float* H    = H0   + (size_t)N * 64;
  float* HW1  = H    + (size_t)N * 64;
  float* HW3  = HW1  + (size_t)N * 64;
  float* Sall = HW3  + (size_t)N * 64;
  float* E0t  = Sall + (size_t)N * 256;
  float* TE   = E0t  + (size_t)NREL * 64;
  float* e1q  = TE   + (size_t)NREL * 64;
  float* feat = e1q  + (size_t)NQ * 64;
  int*   cf   = (int*)(feat + (size_t)NQ * 384);
  int*   cb   = cf + N;
  int*   pos  = cb + N;
  int*   srcf = pos + N;
  int*   rr   = srcf + 2 * (size_t)M;
  int*   qi   = rr   + 2 * (size_t)M;
  int*   bcnt = qi + NQ;

  hipMemsetAsync(cf,   0, (size_t)N  * 4, stream);
  hipMemsetAsync(cb,   0, (size_t)N  * 4, stream);
  hipMemsetAsync(qi,   0, (size_t)NQ * 4, stream);
  hipMemsetAsync(bcnt, 0, (size_t)nb * 4, stream);

  // CSR build + frag table
  k_wprep<<<(NFRAG * 64 + 255) / 256, 256, 0, stream>>>(W_ent, Fhi, Flo);
  k_cnt<<<(M + 255) / 256, 256, 0, stream>>>(ht, cf, cb, M);
  k_scan<<<1, 256, 0, stream>>>(cf, cb, pos, N);
  k_slot<<<(2 * M + 255) / 256, 256, 0, stream>>>(ht, rt, pos, srcf, rr, M);

  // Encoders + eu layer-0 E-table
  k_encm<<<(N + 63) / 64, 256, 0, stream>>>(ef, Fhi, Flo, b_ent, g_ent, be_ent, H0, H, N);
  k_enc<<<(NREL + 15) / 16, 256, 0, stream>>>(rtab, W_ein, b_ein, g_e, be_e, E0t, nullptr, NREL);
  k_xw<<<(NREL + 15) / 16, 256, 0, stream>>>(E0t, eu_W + 64 * 64, eu_b, TE, NREL);

  // ---- layer 0 ----
  k_sum<<<(N + 3) / 4, 256, 0, stream>>>(H, E0t, srcf, rr, pos, cf, cb, Sall, N);
  k_hupd2<<<(N + 15) / 16, 256, 0, stream>>>(H, Sall, cf, cb,
      mp_Wf, mp_Wb, mp_bf, mp_bb, mp_g, mp_be, N);
  k_xw<<<(N + 15) / 16, 256, 0, stream>>>(H, eu_W, nullptr, HW1, N);
  k_xw<<<(N + 15) / 16, 256, 0, stream>>>(H, eu_W + 128 * 64, nullptr, HW3, N);

  // ---- layer 1 (eu fused into pull-sum; no E1 buffer) ----
  k_sum2<<<(N + 3) / 4, 256, 0, stream>>>(H, HW1, HW3, TE, E0t, srcf, rr,
      pos, cf, cb, eu_g, eu_be, Sall, N);

  // qi compaction + query-row E1 (needs pre-update H via HW1/HW3 tables only)
  k_qcount<<<nb, 256, 0, stream>>>(q, bcnt, M);
  k_qscan<<<1, 256, 0, stream>>>(bcnt, nb);
  k_qemit<<<nb, 256, 0, stream>>>(q, bcnt, qi, M, NQ);
  k_eu2q<<<(NQ + 3) / 4, 256, 0, stream>>>(HW1, HW3, TE, E0t, ht, rt, qi,
      eu_g, eu_be, e1q, NQ);

  // layer-1 H update (after e1q no longer needs pre-update H: it uses HW tables)
  k_hupd2<<<(N + 15) / 16, 256, 0, stream>>>(H, Sall, cf, cb,
      mp_Wf + 128 * 64, mp_Wb + 128 * 64, mp_bf + 64, mp_bb + 64,
      mp_g + 64, mp_be + 64, N);

  // features + classifier
  k_feat<<<(NQ + 3) / 4, 256, 0, stream>>>(H, H0, e1q, E0t, rt, ht, qi,
      eu_W + 192 * 64, eu_b + 64, eu_g + 64, eu_be + 64, feat, NQ);
  k_cls<<<(NQ + 3) / 4, 256, 0, stream>>>(feat, clsW1, clsb1, clsW2, clsb2,
      (float*)d_out, NQ);
}

// Round 9
// 1138.440 us; speedup vs baseline: 2.0285x; 1.0164x over previous
//
#include <hip/hip_runtime.h>
#include <hip/hip_bf16.h>
#include <cstdint>

constexpr int IN_DIM = 768;
constexpr int NFRAG  = 96;   // W_ent (768x64) -> 24 kt x 4 n

typedef __attribute__((ext_vector_type(8))) short bf16x8;
typedef __attribute__((ext_vector_type(4))) float f32x4;

static __device__ __forceinline__ float leaky_(float x){ return x >= 0.0f ? x : 0.01f * x; }

static __device__ __forceinline__ float wsum_(float v){
#pragma unroll
  for (int m = 1; m < 64; m <<= 1) v += __shfl_xor(v, m, 64);
  return v;
}

static __device__ __forceinline__ float wln_(float v, float g, float be){
  float mu  = wsum_(v) * 0.015625f;
  float c   = v - mu;
  float var = wsum_(c * c) * 0.015625f;
  return c * rsqrtf(var + 1e-5f) * g + be;
}

static __device__ __forceinline__ unsigned short f2bf(float x){
  return __bfloat16_as_ushort(__float2bfloat16(x));
}
static __device__ __forceinline__ float bf2f(unsigned short u){
  return __bfloat162float(__ushort_as_bfloat16(u));
}
static __device__ __forceinline__ void split4(const float4 a, ushort4& hi, ushort4& lo){
  hi.x = f2bf(a.x); lo.x = f2bf(a.x - bf2f(hi.x));
  hi.y = f2bf(a.y); lo.y = f2bf(a.y - bf2f(hi.y));
  hi.z = f2bf(a.z); lo.z = f2bf(a.z - bf2f(hi.z));
  hi.w = f2bf(a.w); lo.w = f2bf(a.w - bf2f(hi.w));
}

static __device__ __forceinline__ f32x4 mfma3(bf16x8 ah, bf16x8 al, bf16x8 wh, bf16x8 wl, f32x4 acc){
  acc = __builtin_amdgcn_mfma_f32_16x16x32_bf16(ah, wh, acc, 0, 0, 0);
  acc = __builtin_amdgcn_mfma_f32_16x16x32_bf16(al, wh, acc, 0, 0, 0);
  acc = __builtin_amdgcn_mfma_f32_16x16x32_bf16(ah, wl, acc, 0, 0, 0);
  return acc;
}

// ---------------- weight prep (W_ent only): split-bf16 frag table ----------------
__global__ __launch_bounds__(256) void k_wprep(
    const float* __restrict__ Went,
    unsigned short* __restrict__ Fhi, unsigned short* __restrict__ Flo)
{
  const int gt = blockIdx.x * 256 + threadIdx.x;
  if (gt >= NFRAG * 64) return;
  const int fid = gt >> 6, lane = gt & 63;
  const int kt = fid >> 2, nn = fid & 3;
  const int col = nn * 16 + (lane & 15);
  const int r0  = kt * 32 + (lane >> 4) * 8;
  unsigned short* ph = Fhi + ((size_t)fid << 9) + lane * 8;
  unsigned short* pl = Flo + ((size_t)fid << 9) + lane * 8;
#pragma unroll
  for (int j = 0; j < 8; ++j){
    const float v = Went[(size_t)(r0 + j) * 64 + col];
    const unsigned short h = f2bf(v);
    ph[j] = h;
    pl[j] = f2bf(v - bf2f(h));
  }
}

// ---------------- entity encoder (MFMA): H0=H=LN(leaky(X@Went+b)) ----------------
__global__ __launch_bounds__(256) void k_encm(const float* __restrict__ X,
    const unsigned short* __restrict__ Fhi, const unsigned short* __restrict__ Flo,
    const float* __restrict__ b, const float* __restrict__ g_,
    const float* __restrict__ be, float* __restrict__ o0, float* __restrict__ o1, int nrows)
{
  __shared__ unsigned short Ahi[64 * 128];
  __shared__ unsigned short Alo[64 * 128];
  const int tile = blockIdx.x * 64;
  const int tid = threadIdx.x;
  const int w = tid >> 6, lane = tid & 63, g = lane >> 4, lr = lane & 15;
  const int rowb = w * 16;

  f32x4 acc[4];
#pragma unroll
  for (int n = 0; n < 4; ++n){
    const float bv = b[n * 16 + lr];
    acc[n] = (f32x4){bv, bv, bv, bv};
  }

  for (int ch = 0; ch < 6; ++ch){
    __syncthreads();
#pragma unroll
    for (int i = 0; i < 8; ++i){
      const int idx = tid + 256 * i;
      const int row = idx >> 5, c = idx & 31;
      int gr = tile + row; if (gr >= nrows) gr = nrows - 1;
      const float4 a = *(const float4*)&X[(size_t)gr * IN_DIM + ch * 128 + c * 4];
      ushort4 hi, lo; split4(a, hi, lo);
      const int ad = (row * 256 + c * 8) ^ ((row & 7) << 4);
      *(ushort4*)((char*)Ahi + ad) = hi;
      *(ushort4*)((char*)Alo + ad) = lo;
    }
    __syncthreads();

    bf16x8 Ah[4], Al[4];
#pragma unroll
    for (int kt = 0; kt < 4; ++kt){
      const int row = rowb + lr;
      const int ad = (row * 256 + kt * 64 + g * 16) ^ ((row & 7) << 4);
      Ah[kt] = *(const bf16x8*)((const char*)Ahi + ad);
      Al[kt] = *(const bf16x8*)((const char*)Alo + ad);
    }
    const int fb = ch * 16;
#pragma unroll
    for (int n = 0; n < 4; ++n)
#pragma unroll
      for (int kt = 0; kt < 4; ++kt){
        const size_t fo = (((size_t)(fb + kt * 4 + n)) << 9) + lane * 8;
        acc[n] = mfma3(Ah[kt], Al[kt], *(const bf16x8*)(Fhi + fo), *(const bf16x8*)(Flo + fo), acc[n]);
      }
  }

#pragma unroll
  for (int reg = 0; reg < 4; ++reg){
    const int lrow = rowb + g * 4 + reg;
    float v[4];
#pragma unroll
    for (int n = 0; n < 4; ++n) v[n] = leaky_(acc[n][reg]);
    float s = v[0] + v[1] + v[2] + v[3];
#pragma unroll
    for (int msk = 1; msk < 16; msk <<= 1) s += __shfl_xor(s, msk, 64);
    const float mu = s * 0.015625f;
    float q = 0.f;
#pragma unroll
    for (int n = 0; n < 4; ++n){ v[n] -= mu; q += v[n] * v[n]; }
#pragma unroll
    for (int msk = 1; msk < 16; msk <<= 1) q += __shfl_xor(q, msk, 64);
    const float rs = rsqrtf(q * 0.015625f + 1e-5f);
    const int r = tile + lrow;
    if (r < nrows){
#pragma unroll
      for (int n = 0; n < 4; ++n){
        const int col = n * 16 + lr;
        const float o = v[n] * rs * g_[col] + be[col];
        o0[(size_t)r * 64 + col] = o;
        o1[(size_t)r * 64 + col] = o;
      }
    }
  }
}

// ---------------- f32 encoder (rel table, 500 rows) ----------------
__global__ __launch_bounds__(256) void k_enc(const float* __restrict__ X,
    const float* __restrict__ W, const float* __restrict__ b,
    const float* __restrict__ g, const float* __restrict__ be,
    float* __restrict__ o0, float* __restrict__ o1, int nrows)
{
  const int w = threadIdx.x >> 6, d = threadIdx.x & 63;
  const int rbase = blockIdx.x * 16 + w * 4;
  int rows[4];
#pragma unroll
  for (int j = 0; j < 4; ++j){ int r = rbase + j; rows[j] = r < nrows ? r : nrows - 1; }
  float acc[4] = {0.f, 0.f, 0.f, 0.f};
  for (int k4 = 0; k4 < IN_DIM / 4; ++k4){
    const int k = k4 * 4;
    const float w0 = W[(k+0)*64+d], w1 = W[(k+1)*64+d];
    const float w2 = W[(k+2)*64+d], w3 = W[(k+3)*64+d];
#pragma unroll
    for (int j = 0; j < 4; ++j){
      const float4 a = *(const float4*)&X[(size_t)rows[j] * IN_DIM + k];
      acc[j] = fmaf(a.x, w0, fmaf(a.y, w1, fmaf(a.z, w2, fmaf(a.w, w3, acc[j]))));
    }
  }
#pragma unroll
  for (int j = 0; j < 4; ++j){
    const int r = rbase + j;
    if (r < nrows){
      float v = wln_(leaky_(acc[j] + b[d]), g[d], be[d]);
      o0[(size_t)r*64+d] = v;
      if (o1) o1[(size_t)r*64+d] = v;
    }
  }
}

// Generic small matmul: Y[r*outStride + outOff + d] = X(nrows x 64) @ W + bias
__global__ __launch_bounds__(256) void k_xw(const float* __restrict__ X,
    const float* __restrict__ W, const float* __restrict__ bias,
    float* __restrict__ Y, int nrows, int outStride, int outOff)
{
  const int w = threadIdx.x >> 6, d = threadIdx.x & 63;
  const int rbase = blockIdx.x * 16 + w * 4;
  int rows[4];
#pragma unroll
  for (int j = 0; j < 4; ++j){ int r = rbase + j; rows[j] = r < nrows ? r : nrows - 1; }
  const float b0 = bias ? bias[d] : 0.f;
  float acc[4] = {b0, b0, b0, b0};
  for (int k4 = 0; k4 < 16; ++k4){
    const int k = k4 * 4;
    const float w0 = W[(k+0)*64+d], w1 = W[(k+1)*64+d];
    const float w2 = W[(k+2)*64+d], w3 = W[(k+3)*64+d];
#pragma unroll
    for (int j = 0; j < 4; ++j){
      const float4 a = *(const float4*)&X[(size_t)rows[j] * 64 + k];
      acc[j] = fmaf(a.x, w0, fmaf(a.y, w1, fmaf(a.z, w2, fmaf(a.w, w3, acc[j]))));
    }
  }
#pragma unroll
  for (int j = 0; j < 4; ++j){
    const int r = rbase + j;
    if (r < nrows) Y[(size_t)r * outStride + outOff + d] = acc[j];
  }
}

// TE pack: TEP[r*64+d] = { (E0t@euW2+eu_b)[r][d], E0t[r][d] }
__global__ __launch_bounds__(256) void k_tep(const float* __restrict__ E0t,
    const float* __restrict__ W, const float* __restrict__ bias,
    float2* __restrict__ TEP, int nrows)
{
  const int w = threadIdx.x >> 6, d = threadIdx.x & 63;
  const int rbase = blockIdx.x * 16 + w * 4;
  int rows[4];
#pragma unroll
  for (int j = 0; j < 4; ++j){ int r = rbase + j; rows[j] = r < nrows ? r : nrows - 1; }
  const float b0 = bias[d];
  float acc[4] = {b0, b0, b0, b0};
  for (int k4 = 0; k4 < 16; ++k4){
    const int k = k4 * 4;
    const float w0 = W[(k+0)*64+d], w1 = W[(k+1)*64+d];
    const float w2 = W[(k+2)*64+d], w3 = W[(k+3)*64+d];
#pragma unroll
    for (int j = 0; j < 4; ++j){
      const float4 a = *(const float4*)&E0t[(size_t)rows[j] * 64 + k];
      acc[j] = fmaf(a.x, w0, fmaf(a.y, w1, fmaf(a.z, w2, fmaf(a.w, w3, acc[j]))));
    }
  }
#pragma unroll
  for (int j = 0; j < 4; ++j){
    const int r = rbase + j;
    if (r < nrows) TEP[(size_t)r * 64 + d] = make_float2(acc[j], E0t[(size_t)r * 64 + d]);
  }
}

// Degree counts
__global__ __launch_bounds__(256) void k_cnt(const int* __restrict__ ht,
    int* __restrict__ cf, int* __restrict__ cb, int M)
{
  int m = blockIdx.x * 256 + threadIdx.x;
  if (m < M){
    atomicAdd(&cf[ht[2*m+1]], 1);
    atomicAdd(&cb[ht[2*m+0]], 1);
  }
}

__global__ __launch_bounds__(256) void k_scan(const int* __restrict__ cf,
    const int* __restrict__ cb, int* __restrict__ pos, int N)
{
  __shared__ int ws[4];
  const int tid = threadIdx.x, lane = tid & 63, w = tid >> 6;
  const int chunk = (N + 255) / 256;
  int s = 0;
  for (int i = 0; i < chunk; ++i){ int idx = tid * chunk + i; if (idx < N) s += cf[idx] + cb[idx]; }
  int v = s;
#pragma unroll
  for (int off = 1; off < 64; off <<= 1){ int t = __shfl_up(v, off, 64); if (lane >= off) v += t; }
  if (lane == 63) ws[w] = v;
  __syncthreads();
  int wbase = 0;
  for (int i = 0; i < w; ++i) wbase += ws[i];
  int run = wbase + v - s;
  for (int i = 0; i < chunk; ++i){
    int idx = tid * chunk + i;
    if (idx < N){ int t = cf[idx] + cb[idx]; pos[idx] = run; run += t; }
  }
}

// Counting-sort scatter. si[slot] = { src | (fwd<<31), rt[edge] }
__global__ __launch_bounds__(256) void k_slot(const int* __restrict__ ht,
    const int* __restrict__ rt, int* __restrict__ pos,
    int2* __restrict__ si, int M)
{
  const int j = blockIdx.x * 256 + threadIdx.x;
  if (j < 2 * M){
    const int fwd = (j < M) ? 1 : 0;
    const int e = fwd ? j : j - M;
    const int dst = fwd ? ht[2*e+1] : ht[2*e];
    const int src = fwd ? ht[2*e]   : ht[2*e+1];
    const int slot = atomicAdd(&pos[dst], 1);
    si[slot] = make_int2(src | (fwd << 31), rt[e]);
  }
}

// Layer-0 CSR pull-sum (E gathered from E0t by relation)
__global__ __launch_bounds__(256) void k_sum(const float* __restrict__ H,
    const float* __restrict__ E, const int2* __restrict__ si,
    const int* __restrict__ pos_end,
    const int* __restrict__ cf, const int* __restrict__ cb,
    float* __restrict__ Sall, int N)
{
  const int w = threadIdx.x >> 6, lane = threadIdx.x & 63;
  const int n = blockIdx.x * 4 + w;
  if (n >= N) return;
  const int end = pos_end[n];
  const int start = end - (cf[n] + cb[n]);
  float sf = 0.f, ef = 0.f, sb = 0.f, eb = 0.f;
#pragma unroll 4
  for (int i = start; i < end; ++i){
    const int2 sv = si[i];
    const unsigned u = (unsigned)sv.x;
    const int src = (int)(u & 0x7fffffffu);
    const float h = H[(size_t)src * 64 + lane];
    const float e = E[(size_t)sv.y * 64 + lane];
    if (u >> 31){ sf += h; ef += e; }
    else        { sb += h; eb += e; }
  }
  float* S = Sall + (size_t)n * 256;
  S[       lane] = sf;
  S[ 64 + lane] = ef;
  S[128 + lane] = sb;
  S[192 + lane] = eb;
}

// Layer-1 CSR pull-sum with FUSED on-the-fly edge update (no E1 buffer).
// For slot at node n: fwd -> h=src,t=n ; bwd -> h=n,t=src.
// e1 = LN(leaky(HWp[h][0:64]+HWp[t][64:128]+TE[r]) + E0t[r]).
__global__ __launch_bounds__(256) void k_sum2(const float* __restrict__ H,
    const float* __restrict__ HWp, const float2* __restrict__ TEP,
    const int2* __restrict__ si, const int* __restrict__ pos_end,
    const int* __restrict__ cf, const int* __restrict__ cb,
    const float* __restrict__ g0, const float* __restrict__ be0,
    float* __restrict__ Sall, int N)
{
  const int w = threadIdx.x >> 6, lane = threadIdx.x & 63;
  const int n = blockIdx.x * 4 + w;
  if (n >= N) return;
  const int end = pos_end[n];
  const int start = end - (cf[n] + cb[n]);
  const float gg = g0[lane], bb = be0[lane];
  const float hw1n = HWp[(size_t)n * 128 + lane];        // h=n (bwd)
  const float hw3n = HWp[(size_t)n * 128 + 64 + lane];   // t=n (fwd)
  float sf = 0.f, ef = 0.f, sb = 0.f, eb = 0.f;
#pragma unroll 2
  for (int i = start; i < end; ++i){
    const int2 sv = si[i];
    const unsigned u = (unsigned)sv.x;
    const int src = (int)(u & 0x7fffffffu);
    const bool fwd = (u >> 31) != 0;
    const float hv = H[(size_t)src * 64 + lane];
    const float other = HWp[(size_t)src * 128 + (fwd ? 0 : 64) + lane];
    const float2 te = TEP[(size_t)sv.y * 64 + lane];
    float v = (fwd ? other + hw3n : hw1n + other) + te.x;
    v = leaky_(v) + te.y;
    // fused one-pass LN stats: single butterfly for (sum, sumsq)
    float s = v, qq = v * v;
#pragma unroll
    for (int m = 1; m < 64; m <<= 1){
      s  += __shfl_xor(s,  m, 64);
      qq += __shfl_xor(qq, m, 64);
    }
    const float mu  = s * 0.015625f;
    const float var = fmaxf(qq * 0.015625f - mu * mu, 0.f);
    const float e1  = (v - mu) * rsqrtf(var + 1e-5f) * gg + bb;
    if (fwd){ sf += hv; ef += e1; }
    else    { sb += hv; eb += e1; }
  }
  float* S = Sall + (size_t)n * 256;
  S[       lane] = sf;
  S[ 64 + lane] = ef;
  S[128 + lane] = sb;
  S[192 + lane] = eb;
}

// Dense post-aggregation update
__global__ __launch_bounds__(256) void k_hupd2(float* __restrict__ H,
    const float* __restrict__ Sall, const int* __restrict__ cf, const int* __restrict__ cb,
    const float* __restrict__ Wf, const float* __restrict__ Wb,
    const float* __restrict__ bf, const float* __restrict__ bb,
    const float* __restrict__ g, const float* __restrict__ be, int N)
{
  const int w = threadIdx.x >> 6, d = threadIdx.x & 63;
  const int rbase = blockIdx.x * 16 + w * 4;
  int rows[4];
#pragma unroll
  for (int j = 0; j < 4; ++j){ int r = rbase + j; rows[j] = r < N ? r : N - 1; }
  float acc[4];
#pragma unroll
  for (int j = 0; j < 4; ++j)
    acc[j] = (float)cf[rows[j]] * bf[d] + (float)cb[rows[j]] * bb[d];
  for (int k4 = 0; k4 < 64; ++k4){
    const int k = k4 * 4;
    const float* Wsel = (k < 128) ? (Wf + k * 64) : (Wb + (k - 128) * 64);
    const float w0 = Wsel[0*64+d], w1 = Wsel[1*64+d];
    const float w2 = Wsel[2*64+d], w3 = Wsel[3*64+d];
#pragma unroll
    for (int j = 0; j < 4; ++j){
      const float4 a = *(const float4*)&Sall[(size_t)rows[j] * 256 + k];
      acc[j] = fmaf(a.x, w0, fmaf(a.y, w1, fmaf(a.z, w2, fmaf(a.w, w3, acc[j]))));
    }
  }
#pragma unroll
  for (int j = 0; j < 4; ++j){
    const int r = rbase + j;
    if (r < N){
      const float c = (float)(cf[r] + cb[r]);
      const float v = leaky_(acc[j] / c) + H[(size_t)r*64+d];
      H[(size_t)r*64+d] = wln_(v, g[d], be[d]);
    }
  }
}

// Query-rows-only layer-0 edge update
__global__ __launch_bounds__(256) void k_eu2q(const float* __restrict__ HWp,
    const float2* __restrict__ TEP, const int* __restrict__ ht,
    const int* __restrict__ rt, const int* __restrict__ qi,
    const float* __restrict__ g, const float* __restrict__ be,
    float* __restrict__ e1q, int NQ)
{
  const int w = threadIdx.x >> 6, lane = threadIdx.x & 63;
  const int row = blockIdx.x * 4 + w;
  if (row >= NQ) return;
  const int m = qi[row];
  const int h = ht[2*m], t = ht[2*m+1], r = rt[m];
  const float2 te = TEP[(size_t)r * 64 + lane];
  float v = HWp[(size_t)h*128+lane] + HWp[(size_t)t*128+64+lane] + te.x;
  v = leaky_(v) + te.y;
  e1q[(size_t)row*64+lane] = wln_(v, g[lane], be[lane]);
}

// ---- qi compaction ----
__global__ __launch_bounds__(256) void k_qcount(const int* __restrict__ q,
                                                int* __restrict__ bcnt, int M)
{
  const int j = blockIdx.x * 256 + threadIdx.x;
  const int have = (j < M) && (q[j] != 0);
  unsigned long long bal = __ballot(have);
  if ((threadIdx.x & 63) == 0) atomicAdd(&bcnt[blockIdx.x], (int)__popcll(bal));
}

__global__ __launch_bounds__(256) void k_qscan(int* __restrict__ bcnt, int nb)
{
  __shared__ int ws[4];
  const int tid = threadIdx.x, lane = tid & 63, w = tid >> 6;
  const int chunk = (nb + 255) / 256;
  int s = 0;
  for (int i = 0; i < chunk; ++i){ int idx = tid * chunk + i; if (idx < nb) s += bcnt[idx]; }
  int v = s;
#pragma unroll
  for (int off = 1; off < 64; off <<= 1){ int t = __shfl_up(v, off, 64); if (lane >= off) v += t; }
  if (lane == 63) ws[w] = v;
  __syncthreads();
  int wbase = 0;
  for (int i = 0; i < w; ++i) wbase += ws[i];
  int run = wbase + v - s;
  for (int i = 0; i < chunk; ++i){
    int idx = tid * chunk + i;
    if (idx < nb){ int t = bcnt[idx]; bcnt[idx] = run; run += t; }
  }
}

__global__ __launch_bounds__(256) void k_qemit(const int* __restrict__ q,
    const int* __restrict__ bcnt, int* __restrict__ qi, int M, int NQ)
{
  __shared__ int wb[4];
  const int j = blockIdx.x * 256 + threadIdx.x;
  const int lane = threadIdx.x & 63, w = threadIdx.x >> 6;
  const int have = (j < M) && (q[j] != 0);
  unsigned long long bal = __ballot(have);
  if (lane == 0) wb[w] = (int)__popcll(bal);
  __syncthreads();
  int base = bcnt[blockIdx.x];
  for (int i = 0; i < w; ++i) base += wb[i];
  const int rank = base + (int)__popcll(bal & ((1ull << lane) - 1ull));
  if (have && rank < NQ) qi[rank] = j;
}

// Layer-1 edge update at query rows + feature assembly (E1 from e1q).
__global__ __launch_bounds__(256) void k_feat(
    const float* __restrict__ H, const float* __restrict__ H0,
    const float* __restrict__ e1q, const float* __restrict__ E0t,
    const int* __restrict__ rt, const int* __restrict__ ht, const int* __restrict__ qi,
    const float* __restrict__ W, const float* __restrict__ b,
    const float* __restrict__ g, const float* __restrict__ be,
    float* __restrict__ feat, int NQ)
{
  const int w = threadIdx.x >> 6, d = threadIdx.x & 63;
  const int row = blockIdx.x * 4 + w;
  if (row >= NQ) return;
  const int m = qi[row];
  const int h = ht[2*m], t = ht[2*m+1], r = rt[m];
  const float* seg0 = H   + (size_t)h * 64;
  const float* seg1 = e1q + (size_t)row * 64;
  const float* seg2 = H   + (size_t)t * 64;
  float acc = b[d];
  for (int k4 = 0; k4 < 48; ++k4){
    const int k = k4 * 4;
    const float* A = (k4 < 16) ? seg0 : (k4 < 32) ? seg1 - 64 : seg2 - 128;
    const float4 a = *(const float4*)&A[k];
    acc = fmaf(a.x, W[(k+0)*64+d], fmaf(a.y, W[(k+1)*64+d],
          fmaf(a.z, W[(k+2)*64+d], fmaf(a.w, W[(k+3)*64+d], acc))));
  }
  const float ep = seg1[d];
  const float e2 = wln_(leaky_(acc) + ep, g[d], be[d]);
  float* F = feat + (size_t)row * 384;
  F[      d] = e2;
  F[ 64 + d] = E0t[(size_t)r*64+d];
  F[128 + d] = H [(size_t)h*64+d];
  F[192 + d] = H0[(size_t)h*64+d];
  F[256 + d] = H [(size_t)t*64+d];
  F[320 + d] = H0[(size_t)t*64+d];
}

__global__ __launch_bounds__(256) void k_cls(const float* __restrict__ feat,
    const float* __restrict__ W1, const float* __restrict__ b1,
    const float* __restrict__ W2, const float* __restrict__ b2,
    float* __restrict__ out, int NQ)
{
  const int w = threadIdx.x >> 6, d = threadIdx.x & 63;
  const int row = blockIdx.x * 4 + w;
  if (row >= NQ) return;
  const float* F = feat + (size_t)row * 384;
  float acc = b1[d];
  for (int k4 = 0; k4 < 96; ++k4){
    const int k = k4 * 4;
    const float4 a = *(const float4*)&F[k];
    acc = fmaf(a.x, W1[(k+0)*64+d], fmaf(a.y, W1[(k+1)*64+d],
          fmaf(a.z, W1[(k+2)*64+d], fmaf(a.w, W1[(k+3)*64+d], acc))));
  }
  float hs = leaky_(acc) * W2[d];
  hs = wsum_(hs);
  if (d == 0) out[row] = hs + b2[0];
}

extern "C" void kernel_launch(void* const* d_in, const int* in_sizes, int n_in,
                              void* d_out, int out_size, void* d_ws, size_t ws_size,
                              hipStream_t stream)
{
  const int*   ht    = (const int*)  d_in[0];
  const int*   rt    = (const int*)  d_in[1];
  const float* ef    = (const float*)d_in[2];
  const int*   q     = (const int*)  d_in[3];
  const float* rtab  = (const float*)d_in[4];
  const float* W_ent = (const float*)d_in[5];
  const float* b_ent = (const float*)d_in[6];
  const float* g_ent = (const float*)d_in[7];
  const float* be_ent= (const float*)d_in[8];
  const float* W_ein = (const float*)d_in[9];
  const float* b_ein = (const float*)d_in[10];
  const float* g_e   = (const float*)d_in[11];
  const float* be_e  = (const float*)d_in[12];
  const float* mp_Wf = (const float*)d_in[13];
  const float* mp_bf = (const float*)d_in[14];
  const float* mp_Wb = (const float*)d_in[15];
  const float* mp_bb = (const float*)d_in[16];
  const float* mp_g  = (const float*)d_in[17];
  const float* mp_be = (const float*)d_in[18];
  const float* eu_W  = (const float*)d_in[19];
  const float* eu_b  = (const float*)d_in[20];
  const float* eu_g  = (const float*)d_in[21];
  const float* eu_be = (const float*)d_in[22];
  const float* clsW1 = (const float*)d_in[23];
  const float* clsb1 = (const float*)d_in[24];
  const float* clsW2 = (const float*)d_in[25];
  const float* clsb2 = (const float*)d_in[26];

  const int M    = in_sizes[1];
  const int N    = in_sizes[2] / IN_DIM;
  const int NREL = in_sizes[4] / IN_DIM;
  const int NQ   = out_size;
  const int nb   = (M + 255) / 256;

  unsigned short* Fhi = (unsigned short*)d_ws;           // NFRAG*512 ushorts
  unsigned short* Flo = Fhi + (size_t)NFRAG * 512;
  float* H0   = (float*)(Flo + (size_t)NFRAG * 512);
  float* H    = H0   + (size_t)N * 64;
  float* HWp  = H    + (size_t)N * 64;                   // [N][128] = HW1|HW3
  float* Sall = HWp  + (size_t)N * 128;
  float* E0t  = Sall + (size_t)N * 256;
  float2* TEP = (float2*)(E0t + (size_t)NREL * 64);      // [NREL][64] of {TE,E0t}
  float* e1q  = (float*)(TEP + (size_t)NREL * 64);
  float* feat = e1q  + (size_t)NQ * 64;
  int*   cf   = (int*)(feat + (size_t)NQ * 384);
  int*   cb   = cf + N;
  int*   pos  = cb + N;
  int2*  si   = (int2*)(pos + N);                        // [2M]
  int*   qi   = (int*)(si + 2 * (size_t)M);
  int*   bcnt = qi + NQ;

  hipMemsetAsync(cf,   0, (size_t)N  * 4, stream);
  hipMemsetAsync(cb,   0, (size_t)N  * 4, stream);
  hipMemsetAsync(qi,   0, (size_t)NQ * 4, stream);
  hipMemsetAsync(bcnt, 0, (size_t)nb * 4, stream);

  // CSR build + frag table
  k_wprep<<<(NFRAG * 64 + 255) / 256, 256, 0, stream>>>(W_ent, Fhi, Flo);
  k_cnt<<<(M + 255) / 256, 256, 0, stream>>>(ht, cf, cb, M);
  k_scan<<<1, 256, 0, stream>>>(cf, cb, pos, N);
  k_slot<<<(2 * M + 255) / 256, 256, 0, stream>>>(ht, rt, pos, si, M);

  // Encoders + packed eu tables
  k_encm<<<(N + 63) / 64, 256, 0, stream>>>(ef, Fhi, Flo, b_ent, g_ent, be_ent, H0, H, N);
  k_enc<<<(NREL + 15) / 16, 256, 0, stream>>>(rtab, W_ein, b_ein, g_e, be_e, E0t, nullptr, NREL);
  k_tep<<<(NREL + 15) / 16, 256, 0, stream>>>(E0t, eu_W + 64 * 64, eu_b, TEP, NREL);

  // ---- layer 0 ----
  k_sum<<<(N + 3) / 4, 256, 0, stream>>>(H, E0t, si, pos, cf, cb, Sall, N);
  k_hupd2<<<(N + 15) / 16, 256, 0, stream>>>(H, Sall, cf, cb,
      mp_Wf, mp_Wb, mp_bf, mp_bb, mp_g, mp_be, N);
  k_xw<<<(N + 15) / 16, 256, 0, stream>>>(H, eu_W, nullptr, HWp, N, 128, 0);
  k_xw<<<(N + 15) / 16, 256, 0, stream>>>(H, eu_W + 128 * 64, nullptr, HWp, N, 128, 64);

  // ---- layer 1 (eu fused into pull-sum; no E1 buffer) ----
  k_sum2<<<(N + 3) / 4, 256, 0, stream>>>(H, HWp, TEP, si, pos, cf, cb,
      eu_g, eu_be, Sall, N);

  // qi compaction + query-row E1
  k_qcount<<<nb, 256, 0, stream>>>(q, bcnt, M);
  k_qscan<<<1, 256, 0, stream>>>(bcnt, nb);
  k_qemit<<<nb, 256, 0, stream>>>(q, bcnt, qi, M, NQ);
  k_eu2q<<<(NQ + 3) / 4, 256, 0, stream>>>(HWp, TEP, ht, rt, qi,
      eu_g, eu_be, e1q, NQ);

  // layer-1 H update
  k_hupd2<<<(N + 15) / 16, 256, 0, stream>>>(H, Sall, cf, cb,
      mp_Wf + 128 * 64, mp_Wb + 128 * 64, mp_bf + 64, mp_bb + 64,
      mp_g + 64, mp_be + 64, N);

  // features + classifier
  k_feat<<<(NQ + 3) / 4, 256, 0, stream>>>(H, H0, e1q, E0t, rt, ht, qi,
      eu_W + 192 * 64, eu_b + 64, eu_g + 64, eu_be + 64, feat, NQ);
  k_cls<<<(NQ + 3) / 4, 256, 0, stream>>>(feat, clsW1, clsb1, clsW2, clsb2,
      (float*)d_out, NQ);
}

// Round 10
// 967.887 us; speedup vs baseline: 2.3860x; 1.1762x over previous
//
#include <hip/hip_runtime.h>
#include <hip/hip_bf16.h>
#include <cstdint>

constexpr int IN_DIM = 768;
constexpr int FB_ENT = 0;     // 96 frags: W_ent (768x64)
constexpr int FB_L0  = 96;    // 32 frags: [Wf0;Wb0] stacked (256x64)
constexpr int FB_L1  = 128;   // 32 frags: [Wf1;Wb1] stacked (256x64)
constexpr int NFRAG  = 160;

typedef __attribute__((ext_vector_type(8))) short bf16x8;
typedef __attribute__((ext_vector_type(4))) float f32x4;

static __device__ __forceinline__ float leaky_(float x){ return x >= 0.0f ? x : 0.01f * x; }

static __device__ __forceinline__ float wsum_(float v){
#pragma unroll
  for (int m = 1; m < 64; m <<= 1) v += __shfl_xor(v, m, 64);
  return v;
}

static __device__ __forceinline__ float wln_(float v, float g, float be){
  float mu  = wsum_(v) * 0.015625f;
  float c   = v - mu;
  float var = wsum_(c * c) * 0.015625f;
  return c * rsqrtf(var + 1e-5f) * g + be;
}

static __device__ __forceinline__ unsigned short f2bf(float x){
  return __bfloat16_as_ushort(__float2bfloat16(x));
}
static __device__ __forceinline__ float bf2f(unsigned short u){
  return __bfloat162float(__ushort_as_bfloat16(u));
}
static __device__ __forceinline__ void split4(const float4 a, ushort4& hi, ushort4& lo){
  hi.x = f2bf(a.x); lo.x = f2bf(a.x - bf2f(hi.x));
  hi.y = f2bf(a.y); lo.y = f2bf(a.y - bf2f(hi.y));
  hi.z = f2bf(a.z); lo.z = f2bf(a.z - bf2f(hi.z));
  hi.w = f2bf(a.w); lo.w = f2bf(a.w - bf2f(hi.w));
}

static __device__ __forceinline__ f32x4 mfma3(bf16x8 ah, bf16x8 al, bf16x8 wh, bf16x8 wl, f32x4 acc){
  acc = __builtin_amdgcn_mfma_f32_16x16x32_bf16(ah, wh, acc, 0, 0, 0);
  acc = __builtin_amdgcn_mfma_f32_16x16x32_bf16(al, wh, acc, 0, 0, 0);
  acc = __builtin_amdgcn_mfma_f32_16x16x32_bf16(ah, wl, acc, 0, 0, 0);
  return acc;
}

// ---------------- weight prep: split-bf16 frag tables ----------------
// Frag (kt,n): lane l holds W[kt*32 + (l>>4)*8 + j][n*16 + (l&15)], j=0..7.
// [ENT: Went 768x64][L0: [Wf0;Wb0] 256x64][L1: [Wf1;Wb1] 256x64]
__global__ __launch_bounds__(256) void k_wprep(
    const float* __restrict__ Went, const float* __restrict__ Wf,
    const float* __restrict__ Wb,
    unsigned short* __restrict__ Fhi, unsigned short* __restrict__ Flo)
{
  const int gt = blockIdx.x * 256 + threadIdx.x;
  if (gt >= NFRAG * 64) return;
  const int fid = gt >> 6, lane = gt & 63;
  int kind, lf;
  if (fid < FB_L0)      { kind = 0; lf = fid; }
  else if (fid < FB_L1) { kind = 1; lf = fid - FB_L0; }
  else                  { kind = 2; lf = fid - FB_L1; }
  const int kt = lf >> 2, nn = lf & 3;
  const int col = nn * 16 + (lane & 15);
  const int r0  = kt * 32 + (lane >> 4) * 8;
  unsigned short* ph = Fhi + ((size_t)fid << 9) + lane * 8;
  unsigned short* pl = Flo + ((size_t)fid << 9) + lane * 8;
#pragma unroll
  for (int j = 0; j < 8; ++j){
    const int gr = r0 + j;
    const float* rp;
    if (kind == 0)      rp = Went + (size_t)gr * 64;
    else if (kind == 1) rp = (gr < 128) ? Wf + (size_t)gr * 64
                                        : Wb + (size_t)(gr - 128) * 64;
    else                rp = (gr < 128) ? Wf + (size_t)(128 + gr) * 64
                                        : Wb + (size_t)gr * 64;
    const float v = rp[col];
    const unsigned short h = f2bf(v);
    ph[j] = h;
    pl[j] = f2bf(v - bf2f(h));
  }
}

// ---------------- entity encoder (MFMA): H0=H=LN(leaky(X@Went+b)) ----------------
__global__ __launch_bounds__(256) void k_encm(const float* __restrict__ X,
    const unsigned short* __restrict__ Fhi, const unsigned short* __restrict__ Flo,
    const float* __restrict__ b, const float* __restrict__ g_,
    const float* __restrict__ be, float* __restrict__ o0, float* __restrict__ o1, int nrows)
{
  __shared__ unsigned short Ahi[64 * 128];
  __shared__ unsigned short Alo[64 * 128];
  const int tile = blockIdx.x * 64;
  const int tid = threadIdx.x;
  const int w = tid >> 6, lane = tid & 63, g = lane >> 4, lr = lane & 15;
  const int rowb = w * 16;

  f32x4 acc[4];
#pragma unroll
  for (int n = 0; n < 4; ++n){
    const float bv = b[n * 16 + lr];
    acc[n] = (f32x4){bv, bv, bv, bv};
  }

  for (int ch = 0; ch < 6; ++ch){
    __syncthreads();
#pragma unroll
    for (int i = 0; i < 8; ++i){
      const int idx = tid + 256 * i;
      const int row = idx >> 5, c = idx & 31;
      int gr = tile + row; if (gr >= nrows) gr = nrows - 1;
      const float4 a = *(const float4*)&X[(size_t)gr * IN_DIM + ch * 128 + c * 4];
      ushort4 hi, lo; split4(a, hi, lo);
      const int ad = (row * 256 + c * 8) ^ ((row & 7) << 4);
      *(ushort4*)((char*)Ahi + ad) = hi;
      *(ushort4*)((char*)Alo + ad) = lo;
    }
    __syncthreads();

    bf16x8 Ah[4], Al[4];
#pragma unroll
    for (int kt = 0; kt < 4; ++kt){
      const int row = rowb + lr;
      const int ad = (row * 256 + kt * 64 + g * 16) ^ ((row & 7) << 4);
      Ah[kt] = *(const bf16x8*)((const char*)Ahi + ad);
      Al[kt] = *(const bf16x8*)((const char*)Alo + ad);
    }
    const int fb = ch * 16;
#pragma unroll
    for (int n = 0; n < 4; ++n)
#pragma unroll
      for (int kt = 0; kt < 4; ++kt){
        const size_t fo = (((size_t)(fb + kt * 4 + n)) << 9) + lane * 8;
        acc[n] = mfma3(Ah[kt], Al[kt], *(const bf16x8*)(Fhi + fo), *(const bf16x8*)(Flo + fo), acc[n]);
      }
  }

#pragma unroll
  for (int reg = 0; reg < 4; ++reg){
    const int lrow = rowb + g * 4 + reg;
    float v[4];
#pragma unroll
    for (int n = 0; n < 4; ++n) v[n] = leaky_(acc[n][reg]);
    float s = v[0] + v[1] + v[2] + v[3];
#pragma unroll
    for (int msk = 1; msk < 16; msk <<= 1) s += __shfl_xor(s, msk, 64);
    const float mu = s * 0.015625f;
    float q = 0.f;
#pragma unroll
    for (int n = 0; n < 4; ++n){ v[n] -= mu; q += v[n] * v[n]; }
#pragma unroll
    for (int msk = 1; msk < 16; msk <<= 1) q += __shfl_xor(q, msk, 64);
    const float rs = rsqrtf(q * 0.015625f + 1e-5f);
    const int r = tile + lrow;
    if (r < nrows){
#pragma unroll
      for (int n = 0; n < 4; ++n){
        const int col = n * 16 + lr;
        const float o = v[n] * rs * g_[col] + be[col];
        o0[(size_t)r * 64 + col] = o;
        o1[(size_t)r * 64 + col] = o;
      }
    }
  }
}

// ---------------- H update (MFMA): H = LN(leaky((Sall@[Wf;Wb]+cf*bf+cb*bb)/cnt)+H) ----
__global__ __launch_bounds__(256) void k_hupd2m(float* __restrict__ H,
    const float* __restrict__ Sall, const int* __restrict__ cf, const int* __restrict__ cb,
    const unsigned short* __restrict__ Fhi, const unsigned short* __restrict__ Flo, int fb,
    const float* __restrict__ bf, const float* __restrict__ bb,
    const float* __restrict__ g_, const float* __restrict__ be, int N)
{
  __shared__ unsigned short Ahi[64 * 256];
  __shared__ unsigned short Alo[64 * 256];
  const int tile = blockIdx.x * 64, tid = threadIdx.x;
  // stage 64 rows x 64 float4-chunks (K=256): 4096 tasks = 16 x 256
#pragma unroll
  for (int i = 0; i < 16; ++i){
    const int idx = tid + 256 * i;
    const int row = idx >> 6, c = idx & 63;
    int gr = tile + row; if (gr >= N) gr = N - 1;
    const float4 a = *(const float4*)&Sall[(size_t)gr * 256 + c * 4];
    ushort4 hi, lo; split4(a, hi, lo);
    const int ad = (row * 512 + c * 8) ^ ((row & 7) << 4);
    *(ushort4*)((char*)Ahi + ad) = hi;
    *(ushort4*)((char*)Alo + ad) = lo;
  }
  __syncthreads();

  const int w = tid >> 6, lane = tid & 63, g = lane >> 4, lr = lane & 15;
  const int rowb = w * 16;
  bf16x8 Ah[8], Al[8];
#pragma unroll
  for (int kt = 0; kt < 8; ++kt){
    const int row = rowb + lr;
    const int ad = (row * 512 + kt * 64 + g * 16) ^ ((row & 7) << 4);
    Ah[kt] = *(const bf16x8*)((const char*)Ahi + ad);
    Al[kt] = *(const bf16x8*)((const char*)Alo + ad);
  }

  int cfv[4], cbv[4];
#pragma unroll
  for (int reg = 0; reg < 4; ++reg){
    int r = tile + rowb + g * 4 + reg; if (r >= N) r = N - 1;
    cfv[reg] = cf[r]; cbv[reg] = cb[r];
  }
  f32x4 acc[4];
#pragma unroll
  for (int n = 0; n < 4; ++n){
    const float bfc = bf[n * 16 + lr], bbc = bb[n * 16 + lr];
#pragma unroll
    for (int reg = 0; reg < 4; ++reg)
      acc[n][reg] = (float)cfv[reg] * bfc + (float)cbv[reg] * bbc;
  }
#pragma unroll
  for (int n = 0; n < 4; ++n)
#pragma unroll
    for (int kt = 0; kt < 8; ++kt){
      const size_t fo = (((size_t)(fb + kt * 4 + n)) << 9) + lane * 8;
      acc[n] = mfma3(Ah[kt], Al[kt], *(const bf16x8*)(Fhi + fo), *(const bf16x8*)(Flo + fo), acc[n]);
    }

#pragma unroll
  for (int reg = 0; reg < 4; ++reg){
    const int lrow = rowb + g * 4 + reg;
    const int r = tile + lrow;
    const int rr = (r < N) ? r : N - 1;
    const float c = (float)(cfv[reg] + cbv[reg]);
    float v[4];
#pragma unroll
    for (int n = 0; n < 4; ++n)
      v[n] = leaky_(acc[n][reg] / c) + H[(size_t)rr * 64 + n * 16 + lr];
    float s = v[0] + v[1] + v[2] + v[3];
#pragma unroll
    for (int msk = 1; msk < 16; msk <<= 1) s += __shfl_xor(s, msk, 64);
    const float mu = s * 0.015625f;
    float q = 0.f;
#pragma unroll
    for (int n = 0; n < 4; ++n){ v[n] -= mu; q += v[n] * v[n]; }
#pragma unroll
    for (int msk = 1; msk < 16; msk <<= 1) q += __shfl_xor(q, msk, 64);
    const float rs = rsqrtf(q * 0.015625f + 1e-5f);
    if (r < N){
#pragma unroll
      for (int n = 0; n < 4; ++n){
        const int col = n * 16 + lr;
        H[(size_t)r * 64 + col] = v[n] * rs * g_[col] + be[col];
      }
    }
  }
}

// ---------------- f32 encoder (rel table, 500 rows) ----------------
__global__ __launch_bounds__(256) void k_enc(const float* __restrict__ X,
    const float* __restrict__ W, const float* __restrict__ b,
    const float* __restrict__ g, const float* __restrict__ be,
    float* __restrict__ o0, float* __restrict__ o1, int nrows)
{
  const int w = threadIdx.x >> 6, d = threadIdx.x & 63;
  const int rbase = blockIdx.x * 16 + w * 4;
  int rows[4];
#pragma unroll
  for (int j = 0; j < 4; ++j){ int r = rbase + j; rows[j] = r < nrows ? r : nrows - 1; }
  float acc[4] = {0.f, 0.f, 0.f, 0.f};
  for (int k4 = 0; k4 < IN_DIM / 4; ++k4){
    const int k = k4 * 4;
    const float w0 = W[(k+0)*64+d], w1 = W[(k+1)*64+d];
    const float w2 = W[(k+2)*64+d], w3 = W[(k+3)*64+d];
#pragma unroll
    for (int j = 0; j < 4; ++j){
      const float4 a = *(const float4*)&X[(size_t)rows[j] * IN_DIM + k];
      acc[j] = fmaf(a.x, w0, fmaf(a.y, w1, fmaf(a.z, w2, fmaf(a.w, w3, acc[j]))));
    }
  }
#pragma unroll
  for (int j = 0; j < 4; ++j){
    const int r = rbase + j;
    if (r < nrows){
      float v = wln_(leaky_(acc[j] + b[d]), g[d], be[d]);
      o0[(size_t)r*64+d] = v;
      if (o1) o1[(size_t)r*64+d] = v;
    }
  }
}

// Generic small matmul: Y[r*outStride + outOff + d] = X(nrows x 64) @ W + bias
__global__ __launch_bounds__(256) void k_xw(const float* __restrict__ X,
    const float* __restrict__ W, const float* __restrict__ bias,
    float* __restrict__ Y, int nrows, int outStride, int outOff)
{
  const int w = threadIdx.x >> 6, d = threadIdx.x & 63;
  const int rbase = blockIdx.x * 16 + w * 4;
  int rows[4];
#pragma unroll
  for (int j = 0; j < 4; ++j){ int r = rbase + j; rows[j] = r < nrows ? r : nrows - 1; }
  const float b0 = bias ? bias[d] : 0.f;
  float acc[4] = {b0, b0, b0, b0};
  for (int k4 = 0; k4 < 16; ++k4){
    const int k = k4 * 4;
    const float w0 = W[(k+0)*64+d], w1 = W[(k+1)*64+d];
    const float w2 = W[(k+2)*64+d], w3 = W[(k+3)*64+d];
#pragma unroll
    for (int j = 0; j < 4; ++j){
      const float4 a = *(const float4*)&X[(size_t)rows[j] * 64 + k];
      acc[j] = fmaf(a.x, w0, fmaf(a.y, w1, fmaf(a.z, w2, fmaf(a.w, w3, acc[j]))));
    }
  }
#pragma unroll
  for (int j = 0; j < 4; ++j){
    const int r = rbase + j;
    if (r < nrows) Y[(size_t)r * outStride + outOff + d] = acc[j];
  }
}

// TE pack: TEP[r*64+d] = { (E0t@euW2+eu_b)[r][d], E0t[r][d] }
__global__ __launch_bounds__(256) void k_tep(const float* __restrict__ E0t,
    const float* __restrict__ W, const float* __restrict__ bias,
    float2* __restrict__ TEP, int nrows)
{
  const int w = threadIdx.x >> 6, d = threadIdx.x & 63;
  const int rbase = blockIdx.x * 16 + w * 4;
  int rows[4];
#pragma unroll
  for (int j = 0; j < 4; ++j){ int r = rbase + j; rows[j] = r < nrows ? r : nrows - 1; }
  const float b0 = bias[d];
  float acc[4] = {b0, b0, b0, b0};
  for (int k4 = 0; k4 < 16; ++k4){
    const int k = k4 * 4;
    const float w0 = W[(k+0)*64+d], w1 = W[(k+1)*64+d];
    const float w2 = W[(k+2)*64+d], w3 = W[(k+3)*64+d];
#pragma unroll
    for (int j = 0; j < 4; ++j){
      const float4 a = *(const float4*)&E0t[(size_t)rows[j] * 64 + k];
      acc[j] = fmaf(a.x, w0, fmaf(a.y, w1, fmaf(a.z, w2, fmaf(a.w, w3, acc[j]))));
    }
  }
#pragma unroll
  for (int j = 0; j < 4; ++j){
    const int r = rbase + j;
    if (r < nrows) TEP[(size_t)r * 64 + d] = make_float2(acc[j], E0t[(size_t)r * 64 + d]);
  }
}

// Degree counts
__global__ __launch_bounds__(256) void k_cnt(const int* __restrict__ ht,
    int* __restrict__ cf, int* __restrict__ cb, int M)
{
  int m = blockIdx.x * 256 + threadIdx.x;
  if (m < M){
    atomicAdd(&cf[ht[2*m+1]], 1);
    atomicAdd(&cb[ht[2*m+0]], 1);
  }
}

__global__ __launch_bounds__(256) void k_scan(const int* __restrict__ cf,
    const int* __restrict__ cb, int* __restrict__ pos, int N)
{
  __shared__ int ws[4];
  const int tid = threadIdx.x, lane = tid & 63, w = tid >> 6;
  const int chunk = (N + 255) / 256;
  int s = 0;
  for (int i = 0; i < chunk; ++i){ int idx = tid * chunk + i; if (idx < N) s += cf[idx] + cb[idx]; }
  int v = s;
#pragma unroll
  for (int off = 1; off < 64; off <<= 1){ int t = __shfl_up(v, off, 64); if (lane >= off) v += t; }
  if (lane == 63) ws[w] = v;
  __syncthreads();
  int wbase = 0;
  for (int i = 0; i < w; ++i) wbase += ws[i];
  int run = wbase + v - s;
  for (int i = 0; i < chunk; ++i){
    int idx = tid * chunk + i;
    if (idx < N){ int t = cf[idx] + cb[idx]; pos[idx] = run; run += t; }
  }
}

// Counting-sort scatter. si[slot] = { src | (fwd<<31), rt[edge] }
__global__ __launch_bounds__(256) void k_slot(const int* __restrict__ ht,
    const int* __restrict__ rt, int* __restrict__ pos,
    int2* __restrict__ si, int M)
{
  const int j = blockIdx.x * 256 + threadIdx.x;
  if (j < 2 * M){
    const int fwd = (j < M) ? 1 : 0;
    const int e = fwd ? j : j - M;
    const int dst = fwd ? ht[2*e+1] : ht[2*e];
    const int src = fwd ? ht[2*e]   : ht[2*e+1];
    const int slot = atomicAdd(&pos[dst], 1);
    si[slot] = make_int2(src | (fwd << 31), rt[e]);
  }
}

// Layer-0 CSR pull-sum (E gathered from E0t by relation)
__global__ __launch_bounds__(256) void k_sum(const float* __restrict__ H,
    const float* __restrict__ E, const int2* __restrict__ si,
    const int* __restrict__ pos_end,
    const int* __restrict__ cf, const int* __restrict__ cb,
    float* __restrict__ Sall, int N)
{
  const int w = threadIdx.x >> 6, lane = threadIdx.x & 63;
  const int n = blockIdx.x * 4 + w;
  if (n >= N) return;
  const int end = pos_end[n];
  const int start = end - (cf[n] + cb[n]);
  float sf = 0.f, ef = 0.f, sb = 0.f, eb = 0.f;
#pragma unroll 4
  for (int i = start; i < end; ++i){
    const int2 sv = si[i];
    const unsigned u = (unsigned)sv.x;
    const int src = (int)(u & 0x7fffffffu);
    const float h = H[(size_t)src * 64 + lane];
    const float e = E[(size_t)sv.y * 64 + lane];
    if (u >> 31){ sf += h; ef += e; }
    else        { sb += h; eb += e; }
  }
  float* S = Sall + (size_t)n * 256;
  S[       lane] = sf;
  S[ 64 + lane] = ef;
  S[128 + lane] = sb;
  S[192 + lane] = eb;
}

// Layer-1 CSR pull-sum with FUSED on-the-fly edge update (no E1 buffer).
__global__ __launch_bounds__(256) void k_sum2(const float* __restrict__ H,
    const float* __restrict__ HWp, const float2* __restrict__ TEP,
    const int2* __restrict__ si, const int* __restrict__ pos_end,
    const int* __restrict__ cf, const int* __restrict__ cb,
    const float* __restrict__ g0, const float* __restrict__ be0,
    float* __restrict__ Sall, int N)
{
  const int w = threadIdx.x >> 6, lane = threadIdx.x & 63;
  const int n = blockIdx.x * 4 + w;
  if (n >= N) return;
  const int end = pos_end[n];
  const int start = end - (cf[n] + cb[n]);
  const float gg = g0[lane], bb = be0[lane];
  const float hw1n = HWp[(size_t)n * 128 + lane];
  const float hw3n = HWp[(size_t)n * 128 + 64 + lane];
  float sf = 0.f, ef = 0.f, sb = 0.f, eb = 0.f;
#pragma unroll 2
  for (int i = start; i < end; ++i){
    const int2 sv = si[i];
    const unsigned u = (unsigned)sv.x;
    const int src = (int)(u & 0x7fffffffu);
    const bool fwd = (u >> 31) != 0;
    const float hv = H[(size_t)src * 64 + lane];
    const float other = HWp[(size_t)src * 128 + (fwd ? 0 : 64) + lane];
    const float2 te = TEP[(size_t)sv.y * 64 + lane];
    float v = (fwd ? other + hw3n : hw1n + other) + te.x;
    v = leaky_(v) + te.y;
    float s = v, qq = v * v;
#pragma unroll
    for (int m = 1; m < 64; m <<= 1){
      s  += __shfl_xor(s,  m, 64);
      qq += __shfl_xor(qq, m, 64);
    }
    const float mu  = s * 0.015625f;
    const float var = fmaxf(qq * 0.015625f - mu * mu, 0.f);
    const float e1  = (v - mu) * rsqrtf(var + 1e-5f) * gg + bb;
    if (fwd){ sf += hv; ef += e1; }
    else    { sb += hv; eb += e1; }
  }
  float* S = Sall + (size_t)n * 256;
  S[       lane] = sf;
  S[ 64 + lane] = ef;
  S[128 + lane] = sb;
  S[192 + lane] = eb;
}

// Query-rows-only layer-0 edge update
__global__ __launch_bounds__(256) void k_eu2q(const float* __restrict__ HWp,
    const float2* __restrict__ TEP, const int* __restrict__ ht,
    const int* __restrict__ rt, const int* __restrict__ qi,
    const float* __restrict__ g, const float* __restrict__ be,
    float* __restrict__ e1q, int NQ)
{
  const int w = threadIdx.x >> 6, lane = threadIdx.x & 63;
  const int row = blockIdx.x * 4 + w;
  if (row >= NQ) return;
  const int m = qi[row];
  const int h = ht[2*m], t = ht[2*m+1], r = rt[m];
  const float2 te = TEP[(size_t)r * 64 + lane];
  float v = HWp[(size_t)h*128+lane] + HWp[(size_t)t*128+64+lane] + te.x;
  v = leaky_(v) + te.y;
  e1q[(size_t)row*64+lane] = wln_(v, g[lane], be[lane]);
}

// ---- qi compaction ----
__global__ __launch_bounds__(256) void k_qcount(const int* __restrict__ q,
                                                int* __restrict__ bcnt, int M)
{
  const int j = blockIdx.x * 256 + threadIdx.x;
  const int have = (j < M) && (q[j] != 0);
  unsigned long long bal = __ballot(have);
  if ((threadIdx.x & 63) == 0) atomicAdd(&bcnt[blockIdx.x], (int)__popcll(bal));
}

__global__ __launch_bounds__(256) void k_qscan(int* __restrict__ bcnt, int nb)
{
  __shared__ int ws[4];
  const int tid = threadIdx.x, lane = tid & 63, w = tid >> 6;
  const int chunk = (nb + 255) / 256;
  int s = 0;
  for (int i = 0; i < chunk; ++i){ int idx = tid * chunk + i; if (idx < nb) s += bcnt[idx]; }
  int v = s;
#pragma unroll
  for (int off = 1; off < 64; off <<= 1){ int t = __shfl_up(v, off, 64); if (lane >= off) v += t; }
  if (lane == 63) ws[w] = v;
  __syncthreads();
  int wbase = 0;
  for (int i = 0; i < w; ++i) wbase += ws[i];
  int run = wbase + v - s;
  for (int i = 0; i < chunk; ++i){
    int idx = tid * chunk + i;
    if (idx < nb){ int t = bcnt[idx]; bcnt[idx] = run; run += t; }
  }
}

__global__ __launch_bounds__(256) void k_qemit(const int* __restrict__ q,
    const int* __restrict__ bcnt, int* __restrict__ qi, int M, int NQ)
{
  __shared__ int wb[4];
  const int j = blockIdx.x * 256 + threadIdx.x;
  const int lane = threadIdx.x & 63, w = threadIdx.x >> 6;
  const int have = (j < M) && (q[j] != 0);
  unsigned long long bal = __ballot(have);
  if (lane == 0) wb[w] = (int)__popcll(bal);
  __syncthreads();
  int base = bcnt[blockIdx.x];
  for (int i = 0; i < w; ++i) base += wb[i];
  const int rank = base + (int)__popcll(bal & ((1ull << lane) - 1ull));
  if (have && rank < NQ) qi[rank] = j;
}

// Layer-1 edge update at query rows + feature assembly (E1 from e1q).
__global__ __launch_bounds__(256) void k_feat(
    const float* __restrict__ H, const float* __restrict__ H0,
    const float* __restrict__ e1q, const float* __restrict__ E0t,
    const int* __restrict__ rt, const int* __restrict__ ht, const int* __restrict__ qi,
    const float* __restrict__ W, const float* __restrict__ b,
    const float* __restrict__ g, const float* __restrict__ be,
    float* __restrict__ feat, int NQ)
{
  const int w = threadIdx.x >> 6, d = threadIdx.x & 63;
  const int row = blockIdx.x * 4 + w;
  if (row >= NQ) return;
  const int m = qi[row];
  const int h = ht[2*m], t = ht[2*m+1], r = rt[m];
  const float* seg0 = H   + (size_t)h * 64;
  const float* seg1 = e1q + (size_t)row * 64;
  const float* seg2 = H   + (size_t)t * 64;
  float acc = b[d];
  for (int k4 = 0; k4 < 48; ++k4){
    const int k = k4 * 4;
    const float* A = (k4 < 16) ? seg0 : (k4 < 32) ? seg1 - 64 : seg2 - 128;
    const float4 a = *(const float4*)&A[k];
    acc = fmaf(a.x, W[(k+0)*64+d], fmaf(a.y, W[(k+1)*64+d],
          fmaf(a.z, W[(k+2)*64+d], fmaf(a.w, W[(k+3)*64+d], acc))));
  }
  const float ep = seg1[d];
  const float e2 = wln_(leaky_(acc) + ep, g[d], be[d]);
  float* F = feat + (size_t)row * 384;
  F[      d] = e2;
  F[ 64 + d] = E0t[(size_t)r*64+d];
  F[128 + d] = H [(size_t)h*64+d];
  F[192 + d] = H0[(size_t)h*64+d];
  F[256 + d] = H [(size_t)t*64+d];
  F[320 + d] = H0[(size_t)t*64+d];
}

__global__ __launch_bounds__(256) void k_cls(const float* __restrict__ feat,
    const float* __restrict__ W1, const float* __restrict__ b1,
    const float* __restrict__ W2, const float* __restrict__ b2,
    float* __restrict__ out, int NQ)
{
  const int w = threadIdx.x >> 6, d = threadIdx.x & 63;
  const int row = blockIdx.x * 4 + w;
  if (row >= NQ) return;
  const float* F = feat + (size_t)row * 384;
  float acc = b1[d];
  for (int k4 = 0; k4 < 96; ++k4){
    const int k = k4 * 4;
    const float4 a = *(const float4*)&F[k];
    acc = fmaf(a.x, W1[(k+0)*64+d], fmaf(a.y, W1[(k+1)*64+d],
          fmaf(a.z, W1[(k+2)*64+d], fmaf(a.w, W1[(k+3)*64+d], acc))));
  }
  float hs = leaky_(acc) * W2[d];
  hs = wsum_(hs);
  if (d == 0) out[row] = hs + b2[0];
}

extern "C" void kernel_launch(void* const* d_in, const int* in_sizes, int n_in,
                              void* d_out, int out_size, void* d_ws, size_t ws_size,
                              hipStream_t stream)
{
  const int*   ht    = (const int*)  d_in[0];
  const int*   rt    = (const int*)  d_in[1];
  const float* ef    = (const float*)d_in[2];
  const int*   q     = (const int*)  d_in[3];
  const float* rtab  = (const float*)d_in[4];
  const float* W_ent = (const float*)d_in[5];
  const float* b_ent = (const float*)d_in[6];
  const float* g_ent = (const float*)d_in[7];
  const float* be_ent= (const float*)d_in[8];
  const float* W_ein = (const float*)d_in[9];
  const float* b_ein = (const float*)d_in[10];
  const float* g_e   = (const float*)d_in[11];
  const float* be_e  = (const float*)d_in[12];
  const float* mp_Wf = (const float*)d_in[13];
  const float* mp_bf = (const float*)d_in[14];
  const float* mp_Wb = (const float*)d_in[15];
  const float* mp_bb = (const float*)d_in[16];
  const float* mp_g  = (const float*)d_in[17];
  const float* mp_be = (const float*)d_in[18];
  const float* eu_W  = (const float*)d_in[19];
  const float* eu_b  = (const float*)d_in[20];
  const float* eu_g  = (const float*)d_in[21];
  const float* eu_be = (const float*)d_in[22];
  const float* clsW1 = (const float*)d_in[23];
  const float* clsb1 = (const float*)d_in[24];
  const float* clsW2 = (const float*)d_in[25];
  const float* clsb2 = (const float*)d_in[26];

  const int M    = in_sizes[1];
  const int N    = in_sizes[2] / IN_DIM;
  const int NREL = in_sizes[4] / IN_DIM;
  const int NQ   = out_size;
  const int nb   = (M + 255) / 256;

  unsigned short* Fhi = (unsigned short*)d_ws;           // NFRAG*512 ushorts
  unsigned short* Flo = Fhi + (size_t)NFRAG * 512;
  float* H0   = (float*)(Flo + (size_t)NFRAG * 512);
  float* H    = H0   + (size_t)N * 64;
  float* HWp  = H    + (size_t)N * 64;                   // [N][128] = HW1|HW3
  float* Sall = HWp  + (size_t)N * 128;
  float* E0t  = Sall + (size_t)N * 256;
  float2* TEP = (float2*)(E0t + (size_t)NREL * 64);      // [NREL][64] of {TE,E0t}
  float* e1q  = (float*)(TEP + (size_t)NREL * 64);
  float* feat = e1q  + (size_t)NQ * 64;
  int*   cf   = (int*)(feat + (size_t)NQ * 384);
  int*   cb   = cf + N;
  int*   pos  = cb + N;
  int2*  si   = (int2*)(pos + N);                        // [2M]
  int*   qi   = (int*)(si + 2 * (size_t)M);
  int*   bcnt = qi + NQ;

  hipMemsetAsync(cf,   0, (size_t)N  * 4, stream);
  hipMemsetAsync(cb,   0, (size_t)N  * 4, stream);
  hipMemsetAsync(qi,   0, (size_t)NQ * 4, stream);
  hipMemsetAsync(bcnt, 0, (size_t)nb * 4, stream);

  // CSR build + frag tables
  k_wprep<<<(NFRAG * 64 + 255) / 256, 256, 0, stream>>>(W_ent, mp_Wf, mp_Wb, Fhi, Flo);
  k_cnt<<<(M + 255) / 256, 256, 0, stream>>>(ht, cf, cb, M);
  k_scan<<<1, 256, 0, stream>>>(cf, cb, pos, N);
  k_slot<<<(2 * M + 255) / 256, 256, 0, stream>>>(ht, rt, pos, si, M);

  // Encoders + packed eu tables
  k_encm<<<(N + 63) / 64, 256, 0, stream>>>(ef, Fhi, Flo, b_ent, g_ent, be_ent, H0, H, N);
  k_enc<<<(NREL + 15) / 16, 256, 0, stream>>>(rtab, W_ein, b_ein, g_e, be_e, E0t, nullptr, NREL);
  k_tep<<<(NREL + 15) / 16, 256, 0, stream>>>(E0t, eu_W + 64 * 64, eu_b, TEP, NREL);

  // ---- layer 0 ----
  k_sum<<<(N + 3) / 4, 256, 0, stream>>>(H, E0t, si, pos, cf, cb, Sall, N);
  k_hupd2m<<<(N + 63) / 64, 256, 0, stream>>>(H, Sall, cf, cb, Fhi, Flo, FB_L0,
      mp_bf, mp_bb, mp_g, mp_be, N);
  k_xw<<<(N + 15) / 16, 256, 0, stream>>>(H, eu_W, nullptr, HWp, N, 128, 0);
  k_xw<<<(N + 15) / 16, 256, 0, stream>>>(H, eu_W + 128 * 64, nullptr, HWp, N, 128, 64);

  // ---- layer 1 (eu fused into pull-sum; no E1 buffer) ----
  k_sum2<<<(N + 3) / 4, 256, 0, stream>>>(H, HWp, TEP, si, pos, cf, cb,
      eu_g, eu_be, Sall, N);

  // qi compaction + query-row E1
  k_qcount<<<nb, 256, 0, stream>>>(q, bcnt, M);
  k_qscan<<<1, 256, 0, stream>>>(bcnt, nb);
  k_qemit<<<nb, 256, 0, stream>>>(q, bcnt, qi, M, NQ);
  k_eu2q<<<(NQ + 3) / 4, 256, 0, stream>>>(HWp, TEP, ht, rt, qi,
      eu_g, eu_be, e1q, NQ);

  // layer-1 H update
  k_hupd2m<<<(N + 63) / 64, 256, 0, stream>>>(H, Sall, cf, cb, Fhi, Flo, FB_L1,
      mp_bf + 64, mp_bb + 64, mp_g + 64, mp_be + 64, N);

  // features + classifier
  k_feat<<<(NQ + 3) / 4, 256, 0, stream>>>(H, H0, e1q, E0t, rt, ht, qi,
      eu_W + 192 * 64, eu_b + 64, eu_g + 64, eu_be + 64, feat, NQ);
  k_cls<<<(NQ + 3) / 4, 256, 0, stream>>>(feat, clsW1, clsb1, clsW2, clsb2,
      (float*)d_out, NQ);
}